// Round 1
// baseline (1870.995 us; speedup 1.0000x reference)
//
#include <hip/hip_runtime.h>

#define T_LEN 4096
#define HKn   16
#define HVn   32
#define DKn   128
#define DVn   128
#define QKVn  8192

// ---- workspace layout (float element offsets) ----
#define QN_OFF  ((size_t)0)
#define KN_OFF  (QN_OFF + (size_t)T_LEN * HKn * DKn)          // 8388608
#define VA_OFF  (KN_OFF + (size_t)T_LEN * HKn * DKn)          // 16777216
#define DEC_OFF (VA_OFF + (size_t)T_LEN * HVn * DVn)          // 33554432
#define BET_OFF (DEC_OFF + (size_t)T_LEN * HVn)               // 33685504
// total floats = BET_OFF + T_LEN*HVn = 33816576  (~135.3 MB)

// ---------- cross-lane helpers ----------
template <int CTRL>
__device__ __forceinline__ float dpp_add(float x) {
    int v = __builtin_amdgcn_update_dpp(0, __float_as_int(x), CTRL, 0xF, 0xF, true);
    return x + __int_as_float(v);
}

// sum over each 32-lane group (valid for all lanes of the group)
__device__ __forceinline__ float reduce32(float x) {
    x = dpp_add<0x128>(x);   // row_ror:8  (within 16-lane row)
    x = dpp_add<0x124>(x);   // row_ror:4
    x = dpp_add<0x122>(x);   // row_ror:2
    x = dpp_add<0x121>(x);   // row_ror:1  -> full 16-lane sum in all lanes
    int v = __builtin_amdgcn_ds_swizzle(__float_as_int(x), 0x401F); // xor lane^16
    return x + __int_as_float(v);
}

// ---------- prep 1: conv(K=4) + SiLU + (q/k) L2 norm ----------
// grid: (T, 64 segments of 128 ch), block: 128
__global__ __launch_bounds__(128) void prep_conv(
    const float* __restrict__ x,      // [T, QKV]
    const float* __restrict__ w,      // [QKV, 4]
    float* __restrict__ qn,           // [T, HK, DK]
    float* __restrict__ kn,           // [T, HK, DK]
    float* __restrict__ va)           // [T, HV*DV]
{
    const int t   = blockIdx.x;
    const int seg = blockIdx.y;
    const int d   = threadIdx.x;
    const int c   = seg * 128 + d;

    const float4 w4 = ((const float4*)w)[c];   // w[c][0..3]
    float acc = 0.f;
    if (t >= 3) {
        const float* xc = x + (size_t)(t - 3) * QKVn + c;
        acc = fmaf(w4.x, xc[0],
              fmaf(w4.y, xc[(size_t)QKVn],
              fmaf(w4.z, xc[(size_t)2 * QKVn],
                   w4.w * xc[(size_t)3 * QKVn])));
    } else {
        float a0 = (t - 3 >= 0) ? x[(size_t)(t - 3) * QKVn + c] : 0.f;
        float a1 = (t - 2 >= 0) ? x[(size_t)(t - 2) * QKVn + c] : 0.f;
        float a2 = (t - 1 >= 0) ? x[(size_t)(t - 1) * QKVn + c] : 0.f;
        float a3 = x[(size_t)t * QKVn + c];
        acc = fmaf(w4.x, a0, fmaf(w4.y, a1, fmaf(w4.z, a2, w4.w * a3)));
    }
    // SiLU
    const float y = acc / (1.f + __expf(-acc) * 0.f + expf(-acc)); // keep precise expf
    // (the expression above is just acc / (1 + expf(-acc)))

    if (seg < 32) {
        // L2 norm across the 128 channels of this head
        float ss = y * y;
        ss = reduce32(ss);
        __shared__ float part[4];
        if ((threadIdx.x & 31) == 0) part[threadIdx.x >> 5] = ss;
        __syncthreads();
        const float total = part[0] + part[1] + part[2] + part[3];
        const float r = rsqrtf(total + 1e-6f);
        float o = y * r;
        if (seg < 16) {
            o *= 0.08838834764831845f;               // DK^-0.5
            qn[((size_t)t * HKn + seg) * DKn + d] = o;
        } else {
            kn[((size_t)t * HKn + (seg - 16)) * DKn + d] = o;
        }
    } else {
        va[(size_t)t * (HVn * DVn) + (size_t)(seg - 32) * 128 + d] = y;
    }
}

// ---------- prep 2: gating ----------
__global__ __launch_bounds__(256) void prep_gate(
    const float* __restrict__ a,        // [T, HV]
    const float* __restrict__ b,        // [T, HV]
    const float* __restrict__ dt_bias,  // [HV]
    const float* __restrict__ alog,     // [HV]
    float* __restrict__ dec,            // [T, HV] = exp(g)
    float* __restrict__ bet)            // [T, HV] = sigmoid(b)
{
    const int i = blockIdx.x * 256 + threadIdx.x;
    if (i < T_LEN * HVn) {
        const int h = i & (HVn - 1);
        const float xv = a[i] + dt_bias[h];
        const float sp = fmaxf(xv, 0.f) + log1pf(expf(-fabsf(xv)));  // softplus
        const float g  = -expf(alog[h]) * sp;
        dec[i] = expf(g);
        bet[i] = 1.f / (1.f + expf(-b[i]));
    }
}

// ---------- main: gated delta-rule scan ----------
// 4096 independent (head, dv) column recurrences.
// block = 256 threads (4 waves); wave handles 2 columns (32 lanes each, 4 rows/lane).
// grid = 32 heads * 16 column-groups = 512 blocks (2 blocks/CU, 2 waves/SIMD).
__global__ __launch_bounds__(256, 2) void scan_kernel(
    const float* __restrict__ qn,   // [T, HK, DK]
    const float* __restrict__ kn,   // [T, HK, DK]
    const float* __restrict__ va,   // [T, HV*DV]
    const float* __restrict__ dec,  // [T, HV]
    const float* __restrict__ bet,  // [T, HV]
    float* __restrict__ out)        // [T, HV, DV]
{
    const int blk  = blockIdx.x;
    const int h    = blk >> 4;            // value head
    const int cg   = blk & 15;            // column group (8 dv per block)
    const int tid  = threadIdx.x;
    const int wid  = tid >> 6;
    const int lane = tid & 63;
    const int half = lane >> 5;
    const int s    = lane & 31;           // sub-lane within column
    const int dv   = cg * 8 + wid * 2 + half;
    const int kh   = h >> 1;              // GQA: 2 value heads per key head

    const float4* kp = (const float4*)kn + (size_t)kh * (DKn / 4) + s;
    const float4* qp = (const float4*)qn + (size_t)kh * (DKn / 4) + s;
    const float*  vp = va  + (size_t)h * DVn + dv;
    const float*  dp = dec + h;
    const float*  bp = bet + h;
    float*        op = out + (size_t)h * DVn + dv;

    const int KQ_STRIDE = HKn * DKn / 4;  // 512 float4 per t

    float S0 = 0.f, S1 = 0.f, S2 = 0.f, S3 = 0.f;

    // prefetch t = 0
    float4 k4 = kp[0];
    float4 q4 = qp[0];
    float  lam = dp[0];
    float  btv = bp[0];
    float  vv  = vp[0];

    for (int t = 0; t < T_LEN; ++t) {
        const int tn = (t + 1 < T_LEN) ? (t + 1) : t;
        // prefetch next step (hides L1/L2 latency under current compute)
        const float4 k4n = kp[(size_t)tn * KQ_STRIDE];
        const float4 q4n = qp[(size_t)tn * KQ_STRIDE];
        const float  lamn = dp[(size_t)tn * HVn];
        const float  btn  = bp[(size_t)tn * HVn];
        const float  vvn  = vp[(size_t)tn * (HVn * DVn)];

        // pred = lam * (k . S_old), reduced over the 32 lanes of this column
        float pr = fmaf(k4.x, S0, fmaf(k4.y, S1, fmaf(k4.z, S2, k4.w * S3)));
        pr = reduce32(pr);
        const float delta = (vv - lam * pr) * btv;

        // S = lam*S + k*delta
        S0 = fmaf(lam, S0, k4.x * delta);
        S1 = fmaf(lam, S1, k4.y * delta);
        S2 = fmaf(lam, S2, k4.z * delta);
        S3 = fmaf(lam, S3, k4.w * delta);

        // o = q . S
        float o = fmaf(q4.x, S0, fmaf(q4.y, S1, fmaf(q4.z, S2, q4.w * S3)));
        o = reduce32(o);
        if (s == 0) op[(size_t)t * (HVn * DVn)] = o;

        k4 = k4n; q4 = q4n; lam = lamn; btv = btn; vv = vvn;
    }
}

extern "C" void kernel_launch(void* const* d_in, const int* in_sizes, int n_in,
                              void* d_out, int out_size, void* d_ws, size_t ws_size,
                              hipStream_t stream) {
    const float* mixed_qkv = (const float*)d_in[0];
    const float* a         = (const float*)d_in[1];
    const float* b         = (const float*)d_in[2];
    const float* conv_w    = (const float*)d_in[3];
    const float* dt_bias   = (const float*)d_in[4];
    const float* alog      = (const float*)d_in[5];
    float* out = (float*)d_out;
    float* ws  = (float*)d_ws;

    float* qn  = ws + QN_OFF;
    float* knb = ws + KN_OFF;
    float* va  = ws + VA_OFF;
    float* dec = ws + DEC_OFF;
    float* bet = ws + BET_OFF;

    dim3 cgrid(T_LEN, 64);
    prep_conv<<<cgrid, 128, 0, stream>>>(mixed_qkv, conv_w, qn, knb, va);

    prep_gate<<<(T_LEN * HVn + 255) / 256, 256, 0, stream>>>(a, b, dt_bias, alog, dec, bet);

    scan_kernel<<<HVn * 16, 256, 0, stream>>>(qn, knb, va, dec, bet, out);
}

// Round 2
// 1130.926 us; speedup vs baseline: 1.6544x; 1.6544x over previous
//
#include <hip/hip_runtime.h>

#define T_LEN 4096
#define HKn   16
#define HVn   32
#define DKn   128
#define DVn   128
#define QKVn  8192
#define TB    32
#define NT    (T_LEN / TB)   // 128

// ---- workspace layout (float element offsets) ----
#define QN_OFF  ((size_t)0)
#define KN_OFF  (QN_OFF + (size_t)T_LEN * HKn * DKn)
#define VA_OFF  (KN_OFF + (size_t)T_LEN * HKn * DKn)
#define DEC_OFF (VA_OFF + (size_t)T_LEN * HVn * DVn)
#define BET_OFF (DEC_OFF + (size_t)T_LEN * HVn)

// ---------- cross-lane helpers ----------
template <int CTRL>
__device__ __forceinline__ float dpp_add(float x) {
    int v = __builtin_amdgcn_update_dpp(0, __float_as_int(x), CTRL, 0xF, 0xF, true);
    return x + __int_as_float(v);
}

// sum over each 32-lane group (valid for all lanes of the group)
__device__ __forceinline__ float reduce32(float x) {
    x = dpp_add<0x128>(x);   // row_ror:8
    x = dpp_add<0x124>(x);   // row_ror:4
    x = dpp_add<0x122>(x);   // row_ror:2
    x = dpp_add<0x121>(x);   // row_ror:1  -> 16-lane sum in all lanes
    int v = __builtin_amdgcn_ds_swizzle(__float_as_int(x), 0x401F); // xor lane^16
    return x + __int_as_float(v);
}

// ---------- global->LDS async ----------
typedef __attribute__((address_space(3))) void lds_t;
typedef const __attribute__((address_space(1))) void gbl_t;
__device__ __forceinline__ void load_lds16(const void* g, void* l) {
    __builtin_amdgcn_global_load_lds((gbl_t*)g, (lds_t*)l, 16, 0, 0);
}
__device__ __forceinline__ void load_lds4(const void* g, void* l) {
    __builtin_amdgcn_global_load_lds((gbl_t*)g, (lds_t*)l, 4, 0, 0);
}

// ---------- prep 1: conv(K=4) + SiLU + (q/k) L2 norm ----------
__global__ __launch_bounds__(128) void prep_conv(
    const float* __restrict__ x,      // [T, QKV]
    const float* __restrict__ w,      // [QKV, 4]
    float* __restrict__ qn,           // [T, HK, DK]
    float* __restrict__ kn,           // [T, HK, DK]
    float* __restrict__ va)           // [T, HV*DV]
{
    const int t   = blockIdx.x;
    const int seg = blockIdx.y;
    const int d   = threadIdx.x;
    const int c   = seg * 128 + d;

    const float4 w4 = ((const float4*)w)[c];
    float acc;
    if (t >= 3) {
        const float* xc = x + (size_t)(t - 3) * QKVn + c;
        acc = fmaf(w4.x, xc[0],
              fmaf(w4.y, xc[(size_t)QKVn],
              fmaf(w4.z, xc[(size_t)2 * QKVn],
                   w4.w * xc[(size_t)3 * QKVn])));
    } else {
        float a0 = (t - 3 >= 0) ? x[(size_t)(t - 3) * QKVn + c] : 0.f;
        float a1 = (t - 2 >= 0) ? x[(size_t)(t - 2) * QKVn + c] : 0.f;
        float a2 = (t - 1 >= 0) ? x[(size_t)(t - 1) * QKVn + c] : 0.f;
        float a3 = x[(size_t)t * QKVn + c];
        acc = fmaf(w4.x, a0, fmaf(w4.y, a1, fmaf(w4.z, a2, w4.w * a3)));
    }
    const float y = acc / (1.f + expf(-acc));   // SiLU

    if (seg < 32) {
        float ss = y * y;
        ss = reduce32(ss);
        __shared__ float part[4];
        if ((threadIdx.x & 31) == 0) part[threadIdx.x >> 5] = ss;
        __syncthreads();
        const float total = part[0] + part[1] + part[2] + part[3];
        const float r = rsqrtf(total + 1e-6f);
        float o = y * r;
        if (seg < 16) {
            o *= 0.08838834764831845f;               // DK^-0.5
            qn[((size_t)t * HKn + seg) * DKn + d] = o;
        } else {
            kn[((size_t)t * HKn + (seg - 16)) * DKn + d] = o;
        }
    } else {
        va[(size_t)t * (HVn * DVn) + (size_t)(seg - 32) * 128 + d] = y;
    }
}

// ---------- prep 2: gating ----------
__global__ __launch_bounds__(256) void prep_gate(
    const float* __restrict__ a,
    const float* __restrict__ b,
    const float* __restrict__ dt_bias,
    const float* __restrict__ alog,
    float* __restrict__ dec,            // exp(g)
    float* __restrict__ bet)            // sigmoid(b)
{
    const int i = blockIdx.x * 256 + threadIdx.x;
    if (i < T_LEN * HVn) {
        const int h = i & (HVn - 1);
        const float xv = a[i] + dt_bias[h];
        const float sp = fmaxf(xv, 0.f) + log1pf(expf(-fabsf(xv)));
        const float g  = -expf(alog[h]) * sp;
        dec[i] = expf(g);
        bet[i] = 1.f / (1.f + expf(-b[i]));
    }
}

// ---------- main: gated delta-rule scan, LDS-staged double-buffer ----------
__global__ __launch_bounds__(256, 2) void scan_kernel(
    const float* __restrict__ qn,   // [T, HK, DK]
    const float* __restrict__ kn,   // [T, HK, DK]
    const float* __restrict__ va,   // [T, HV*DV]
    const float* __restrict__ dec,  // [T, HV]
    const float* __restrict__ bet,  // [T, HV]
    float* __restrict__ out)        // [T, HV, DV]
{
    __shared__ float sk[2][TB][DKn];
    __shared__ float sq[2][TB][DKn];
    __shared__ float sv[2][TB][8];
    __shared__ float sg[2][TB];
    __shared__ float sb[2][TB];

    // bijective XCD swizzle: 512 blocks, 8 XCDs -> 64 consecutive logical blocks/XCD
    const int nwg = gridDim.x;
    int blk = blockIdx.x;
    blk = (blk & 7) * (nwg >> 3) + (blk >> 3);

    const int h    = blk >> 4;            // value head
    const int cg   = blk & 15;            // column group (8 dv)
    const int tid  = threadIdx.x;
    const int wid  = tid >> 6;
    const int lane = tid & 63;
    const int hf   = lane >> 5;
    const int s    = lane & 31;
    const int col  = wid * 2 + hf;        // 0..7
    const int dv0  = cg * 8;
    const int kh   = h >> 1;

    // each wave issues exactly 10 global_load_lds per stage
    auto stage = [&](int bufi, int t0) {
        const int r0 = wid * 8;
        #pragma unroll
        for (int i = 0; i < 4; ++i) {
            const int r = r0 + 2 * i + (lane >> 5);
            const float* g = kn + ((size_t)(t0 + r) * HKn + kh) * DKn + (size_t)(lane & 31) * 4;
            load_lds16(g, &sk[bufi][r0 + 2 * i][0]);
        }
        #pragma unroll
        for (int i = 0; i < 4; ++i) {
            const int r = r0 + 2 * i + (lane >> 5);
            const float* g = qn + ((size_t)(t0 + r) * HKn + kh) * DKn + (size_t)(lane & 31) * 4;
            load_lds16(g, &sq[bufi][r0 + 2 * i][0]);
        }
        {   // v: rows r0..r0+7, 8 floats each
            const int tt = r0 + (lane >> 3);
            const float* g = va + (size_t)(t0 + tt) * (HVn * DVn) + (size_t)h * DVn + dv0 + (lane & 7);
            load_lds4(g, &sv[bufi][r0][0]);
        }
        if ((wid & 1) == 0) {
            if (lane < 32) {
                const float* g = dec + (size_t)(t0 + lane) * HVn + h;
                load_lds4(g, &sg[bufi][0]);
            }
        } else {
            if (lane < 32) {
                const float* g = bet + (size_t)(t0 + lane) * HVn + h;
                load_lds4(g, &sb[bufi][0]);
            }
        }
    };

    float S0 = 0.f, S1 = 0.f, S2 = 0.f, S3 = 0.f;
    float* op = out + (size_t)h * DVn + dv0 + col;

    stage(0, 0);
    stage(1, TB);
    asm volatile("s_waitcnt vmcnt(10)" ::: "memory");
    __builtin_amdgcn_s_barrier();
    __builtin_amdgcn_sched_barrier(0);

    int cur = 0;
    for (int tile = 0; tile < NT; ++tile) {
        const int t0 = tile * TB;
        #pragma unroll 4
        for (int tt = 0; tt < TB; ++tt) {
            const float4 k4 = *(const float4*)&sk[cur][tt][4 * s];
            const float4 q4 = *(const float4*)&sq[cur][tt][4 * s];
            const float lam = sg[cur][tt];
            const float btv = sb[cur][tt];
            const float vv  = sv[cur][tt][col];

            const float av = vv * btv;     // off-chain
            const float cv = lam * btv;    // off-chain
            const float e0 = lam * S0, e1 = lam * S1, e2 = lam * S2, e3 = lam * S3;

            float pr = fmaf(k4.x, S0, k4.y * S1) + fmaf(k4.z, S2, k4.w * S3);
            pr = reduce32(pr);
            const float delta = fmaf(-cv, pr, av);

            S0 = fmaf(k4.x, delta, e0);
            S1 = fmaf(k4.y, delta, e1);
            S2 = fmaf(k4.z, delta, e2);
            S3 = fmaf(k4.w, delta, e3);

            float o = fmaf(q4.x, S0, q4.y * S1) + fmaf(q4.z, S2, q4.w * S3);
            o = reduce32(o);
            if (s == 0) op[(size_t)(t0 + tt) * (HVn * DVn)] = o;
        }

        asm volatile("" ::: "memory");
        __builtin_amdgcn_s_barrier();          // all waves done reading buf[cur]
        __builtin_amdgcn_sched_barrier(0);
        if (tile + 2 < NT) {
            stage(cur, (tile + 2) * TB);       // refill freed buffer
            asm volatile("s_waitcnt vmcnt(10)" ::: "memory");  // tile+1 loads landed
        } else {
            asm volatile("s_waitcnt vmcnt(0)" ::: "memory");
        }
        __builtin_amdgcn_s_barrier();          // everyone's next buffer ready
        __builtin_amdgcn_sched_barrier(0);
        cur ^= 1;
    }
}

extern "C" void kernel_launch(void* const* d_in, const int* in_sizes, int n_in,
                              void* d_out, int out_size, void* d_ws, size_t ws_size,
                              hipStream_t stream) {
    const float* mixed_qkv = (const float*)d_in[0];
    const float* a         = (const float*)d_in[1];
    const float* b         = (const float*)d_in[2];
    const float* conv_w    = (const float*)d_in[3];
    const float* dt_bias   = (const float*)d_in[4];
    const float* alog      = (const float*)d_in[5];
    float* out = (float*)d_out;
    float* ws  = (float*)d_ws;

    float* qn  = ws + QN_OFF;
    float* knb = ws + KN_OFF;
    float* va  = ws + VA_OFF;
    float* dec = ws + DEC_OFF;
    float* bet = ws + BET_OFF;

    dim3 cgrid(T_LEN, 64);
    prep_conv<<<cgrid, 128, 0, stream>>>(mixed_qkv, conv_w, qn, knb, va);

    prep_gate<<<(T_LEN * HVn + 255) / 256, 256, 0, stream>>>(a, b, dt_bias, alog, dec, bet);

    scan_kernel<<<HVn * 16, 256, 0, stream>>>(qn, knb, va, dec, bet, out);
}

// Round 4
// 946.526 us; speedup vs baseline: 1.9767x; 1.1948x over previous
//
#include <hip/hip_runtime.h>

#define T_LEN 4096
#define HKn   16
#define HVn   32
#define DKn   128
#define DVn   128
#define QKVn  8192
#define TB    32
#define NT    (T_LEN / TB)   // 128

// ---- workspace layout (float element offsets), HEAD-MAJOR ----
// qn2: [HK][T][DK]   kn2: [HK][T][DK]   va2: [HV][T][DV]   gb: [HV][T][2]
#define QN_OFF  ((size_t)0)
#define KN_OFF  (QN_OFF + (size_t)HKn * T_LEN * DKn)
#define VA_OFF  (KN_OFF + (size_t)HKn * T_LEN * DKn)
#define GB_OFF  (VA_OFF + (size_t)HVn * T_LEN * DVn)
// total floats = GB_OFF + T*HV*2 = 33,816,576 (~135.3 MB)

// ---------- cross-lane helpers ----------
template <int CTRL>
__device__ __forceinline__ float dpp_add(float x) {
    int v = __builtin_amdgcn_update_dpp(0, __float_as_int(x), CTRL, 0xF, 0xF, true);
    return x + __int_as_float(v);
}
// allreduce within each 16-lane row
__device__ __forceinline__ float reduce_row16(float x) {
    x = dpp_add<0x128>(x);   // row_ror:8
    x = dpp_add<0x124>(x);   // row_ror:4
    x = dpp_add<0x122>(x);   // row_ror:2
    x = dpp_add<0x121>(x);   // row_ror:1
    return x;
}
// sum over each contiguous 32-lane group (lanes 0-31 / 32-63), valid in all lanes
__device__ __forceinline__ float reduce32g(float x) {
    x = reduce_row16(x);
    int v = __builtin_amdgcn_ds_swizzle(__float_as_int(x), 0x401F); // xor lane^16
    return x + __int_as_float(v);
}
// x[lane] + x[lane^32], all lanes (pure VALU)
__device__ __forceinline__ float xsum32(float x) {
#if __has_builtin(__builtin_amdgcn_permlane32_swap)
    typedef unsigned uv2 __attribute__((ext_vector_type(2)));
    uv2 r = __builtin_amdgcn_permlane32_swap(__float_as_uint(x), __float_as_uint(x), false, false);
    return __uint_as_float(r.x) + __uint_as_float(r.y);
#else
    return x + __shfl_xor(x, 32, 64);
#endif
}
// scan-kernel column sum: column lanes are rows {0,2} (colA) / {1,3} (colB)
__device__ __forceinline__ float reduce32s(float x) { return xsum32(reduce_row16(x)); }

// ---------- prep 1: conv(K=4) + SiLU + (q/k) L2 norm, head-major stores ----------
__global__ __launch_bounds__(128) void prep_conv(
    const float* __restrict__ x,      // [T, QKV]
    const float* __restrict__ w,      // [QKV, 4]
    float* __restrict__ qn2,          // [HK][T][DK]
    float* __restrict__ kn2,          // [HK][T][DK]
    float* __restrict__ va2)          // [HV][T][DV]
{
    const int t   = blockIdx.x;
    const int seg = blockIdx.y;
    const int d   = threadIdx.x;
    const int c   = seg * 128 + d;

    const float4 w4 = ((const float4*)w)[c];
    float acc;
    if (t >= 3) {
        const float* xc = x + (size_t)(t - 3) * QKVn + c;
        acc = fmaf(w4.x, xc[0],
              fmaf(w4.y, xc[(size_t)QKVn],
              fmaf(w4.z, xc[(size_t)2 * QKVn],
                   w4.w * xc[(size_t)3 * QKVn])));
    } else {
        float a0 = (t - 3 >= 0) ? x[(size_t)(t - 3) * QKVn + c] : 0.f;
        float a1 = (t - 2 >= 0) ? x[(size_t)(t - 2) * QKVn + c] : 0.f;
        float a2 = (t - 1 >= 0) ? x[(size_t)(t - 1) * QKVn + c] : 0.f;
        float a3 = x[(size_t)t * QKVn + c];
        acc = fmaf(w4.x, a0, fmaf(w4.y, a1, fmaf(w4.z, a2, w4.w * a3)));
    }
    const float y = acc / (1.f + expf(-acc));   // SiLU

    if (seg < 32) {
        // L2 norm over this head's 128 channels (= all 128 threads of the block)
        float ss = reduce32g(y * y);            // per-32-lane-group sums
        __shared__ float part[4];
        if ((threadIdx.x & 31) == 0) part[threadIdx.x >> 5] = ss;
        __syncthreads();
        const float total = part[0] + part[1] + part[2] + part[3];
        const float r = rsqrtf(total + 1e-6f);
        float o = y * r;
        if (seg < 16) {
            o *= 0.08838834764831845f;               // DK^-0.5
            qn2[((size_t)seg * T_LEN + t) * DKn + d] = o;
        } else {
            kn2[((size_t)(seg - 16) * T_LEN + t) * DKn + d] = o;
        }
    } else {
        va2[((size_t)(seg - 32) * T_LEN + t) * DVn + d] = y;
    }
}

// ---------- prep 2: gating, packed (lambda, beta) head-major ----------
__global__ __launch_bounds__(256) void prep_gate(
    const float* __restrict__ a,        // [T, HV]
    const float* __restrict__ b,        // [T, HV]
    const float* __restrict__ dt_bias,  // [HV]
    const float* __restrict__ alog,     // [HV]
    float2* __restrict__ gb)            // [HV][T] of (exp(g), sigmoid(b))
{
    const int i = blockIdx.x * 256 + threadIdx.x;
    if (i < T_LEN * HVn) {
        const int t = i & (T_LEN - 1);
        const int h = i >> 12;
        const float av = a[(size_t)t * HVn + h];
        const float bv = b[(size_t)t * HVn + h];
        const float xv = av + dt_bias[h];
        const float sp = fmaxf(xv, 0.f) + log1pf(expf(-fabsf(xv)));
        const float g  = -expf(alog[h]) * sp;
        gb[(size_t)h * T_LEN + t] = make_float2(expf(g), 1.f / (1.f + expf(-bv)));
    }
}

// ---------- main: free-running scan, 8-deep register prefetch, no LDS ----------
#define STEPB(ST, J, PF) { \
    const float4 k4 = kb[J]; const float4 q4 = qb[J]; \
    const float  vv = vb[J]; const float2 g2 = gbb[J]; \
    kb[J]  = *(const float4*)(kT + (PF) * DKn); \
    qb[J]  = *(const float4*)(qT + (PF) * DKn); \
    vb[J]  = vT[(PF) * DVn]; \
    gbb[J] = *(const float2*)(gT + (PF) * 2); \
    const float lam = g2.x, btv = g2.y; \
    float pr = fmaf(k4.x, S0, k4.y * S1) + fmaf(k4.z, S2, k4.w * S3); \
    pr = reduce32s(pr); \
    const float dl = fmaf(-(lam * btv), pr, vv * btv); \
    S0 = fmaf(lam, S0, k4.x * dl); S1 = fmaf(lam, S1, k4.y * dl); \
    S2 = fmaf(lam, S2, k4.z * dl); S3 = fmaf(lam, S3, k4.w * dl); \
    float oo = fmaf(q4.x, S0, q4.y * S1) + fmaf(q4.z, S2, q4.w * S3); \
    oo = reduce32s(oo); \
    okeep = (sp == (ST)) ? oo : okeep; \
}

__global__ __launch_bounds__(256) void scan_kernel(
    const float* __restrict__ qn2,  // [HK][T][DK]
    const float* __restrict__ kn2,  // [HK][T][DK]
    const float* __restrict__ va2,  // [HV][T][DV]
    const float* __restrict__ gb,   // [HV][T][2]
    float* __restrict__ out)        // [T, HV, DV]
{
    // bijective XCD swizzle: 512 blocks -> 64 consecutive logical blocks per XCD
    int blk = blockIdx.x;
    blk = (blk & 7) * 64 + (blk >> 3);

    const int h    = blk >> 4;             // value head
    const int cg   = blk & 15;             // column group (8 dv)
    const int tid  = threadIdx.x;
    const int wid  = tid >> 6;
    const int lane = tid & 63;
    const int col  = (lane >> 4) & 1;      // colA = rows{0,2}, colB = rows{1,3}
    const int sp   = (lane & 15) | ((lane >> 5) << 4);   // 0..31 dim-slice index
    const int dv   = cg * 8 + wid * 2 + col;
    const int kh   = h >> 1;

    const float* kB = kn2 + (size_t)kh * T_LEN * DKn + (size_t)sp * 4;
    const float* qB = qn2 + (size_t)kh * T_LEN * DKn + (size_t)sp * 4;
    const float* vB = va2 + (size_t)h  * T_LEN * DVn + dv;
    const float* gB = gb  + (size_t)h  * T_LEN * 2;
    float*       oB = out + (size_t)sp * (HVn * DVn) + (size_t)h * DVn + dv;

    float S0 = 0.f, S1 = 0.f, S2 = 0.f, S3 = 0.f;
    float4 kb[8], qb[8];
    float  vb[8];
    float2 gbb[8];

    #pragma unroll
    for (int j = 0; j < 8; ++j) {
        kb[j]  = *(const float4*)(kB + (size_t)j * DKn);
        qb[j]  = *(const float4*)(qB + (size_t)j * DKn);
        vb[j]  = vB[(size_t)j * DVn];
        gbb[j] = *(const float2*)(gB + (size_t)j * 2);
    }

    const float* kT = kB; const float* qT = qB;
    const float* vT = vB; const float* gT = gB;

    for (int tile = 0; tile < NT - 1; ++tile) {
        float okeep = 0.f;
        #pragma unroll
        for (int u = 0; u < 4; ++u) {
            #pragma unroll
            for (int j = 0; j < 8; ++j) {
                STEPB(u * 8 + j, j, j + 8);
            }
            kT += 8 * DKn; qT += 8 * DKn; vT += 8 * DVn; gT += 16;
        }
        oB[(size_t)(tile * TB) * (HVn * DVn)] = okeep;
    }
    {   // last tile (t0 = 4064): clamp prefetch at final row
        const int tile = NT - 1;
        float okeep = 0.f;
        #pragma unroll
        for (int u = 0; u < 4; ++u) {
            #pragma unroll
            for (int j = 0; j < 8; ++j) {
                const int pfr = (u == 3) ? 7 : (j + 8);
                STEPB(u * 8 + j, j, pfr);
            }
            kT += 8 * DKn; qT += 8 * DKn; vT += 8 * DVn; gT += 16;
        }
        oB[(size_t)(tile * TB) * (HVn * DVn)] = okeep;
    }
}

extern "C" void kernel_launch(void* const* d_in, const int* in_sizes, int n_in,
                              void* d_out, int out_size, void* d_ws, size_t ws_size,
                              hipStream_t stream) {
    const float* mixed_qkv = (const float*)d_in[0];
    const float* a         = (const float*)d_in[1];
    const float* b         = (const float*)d_in[2];
    const float* conv_w    = (const float*)d_in[3];
    const float* dt_bias   = (const float*)d_in[4];
    const float* alog      = (const float*)d_in[5];
    float* out = (float*)d_out;
    float* ws  = (float*)d_ws;

    float* qn2 = ws + QN_OFF;
    float* kn2 = ws + KN_OFF;
    float* va2 = ws + VA_OFF;
    float* gbp = ws + GB_OFF;

    dim3 cgrid(T_LEN, 64);
    prep_conv<<<cgrid, 128, 0, stream>>>(mixed_qkv, conv_w, qn2, kn2, va2);

    prep_gate<<<(T_LEN * HVn + 255) / 256, 256, 0, stream>>>(a, b, dt_bias, alog,
                                                             (float2*)gbp);

    scan_kernel<<<HVn * 16, 256, 0, stream>>>(qn2, kn2, va2, gbp, out);
}

// Round 5
// 841.285 us; speedup vs baseline: 2.2240x; 1.1251x over previous
//
#include <hip/hip_runtime.h>

#define T_LEN 4096
#define HKn   16
#define HVn   32
#define DKn   128
#define DVn   128
#define QKVn  8192
#define GS    8             // steps per register group
#define NG    (T_LEN / GS)  // 512 groups
#define TBO   32            // output-keep period (steps)
#define NTI   (T_LEN / TBO) // 128 tiles (4 groups each)

// ---- workspace layout (float element offsets), HEAD-MAJOR ----
// qn2: [HK][T][DK]  kn2: [HK][T][DK]  va2: [HV][T][DV] (= beta*v)  gb: [HV][T][2] (= lam, lam*beta)
#define QN_OFF  ((size_t)0)
#define KN_OFF  (QN_OFF + (size_t)HKn * T_LEN * DKn)
#define VA_OFF  (KN_OFF + (size_t)HKn * T_LEN * DKn)
#define GB_OFF  (VA_OFF + (size_t)HVn * T_LEN * DVn)

// ---------- cross-lane helpers ----------
template <int CTRL>
__device__ __forceinline__ float dpp_add(float x) {
    int v = __builtin_amdgcn_update_dpp(0, __float_as_int(x), CTRL, 0xF, 0xF, true);
    return x + __int_as_float(v);
}
__device__ __forceinline__ float reduce_row16(float x) {
    x = dpp_add<0x128>(x);   // row_ror:8
    x = dpp_add<0x124>(x);   // row_ror:4
    x = dpp_add<0x122>(x);   // row_ror:2
    x = dpp_add<0x121>(x);   // row_ror:1
    return x;
}
// sum over each contiguous 32-lane group, valid in all lanes (prep kernel)
__device__ __forceinline__ float reduce32g(float x) {
    x = reduce_row16(x);
    int v = __builtin_amdgcn_ds_swizzle(__float_as_int(x), 0x401F); // xor lane^16
    return x + __int_as_float(v);
}
// x[lane] + x[lane^32], all lanes (pure VALU)
__device__ __forceinline__ float xsum32(float x) {
#if __has_builtin(__builtin_amdgcn_permlane32_swap)
    typedef unsigned uv2 __attribute__((ext_vector_type(2)));
    uv2 r = __builtin_amdgcn_permlane32_swap(__float_as_uint(x), __float_as_uint(x), false, false);
    return __uint_as_float(r.x) + __uint_as_float(r.y);
#else
    return x + __shfl_xor(x, 32, 64);
#endif
}
// scan column sum: column lanes are rows {0,2} (colA) / {1,3} (colB)
__device__ __forceinline__ float reduce32s(float x) { return xsum32(reduce_row16(x)); }

// ---------- prep 1: conv(K=4) + SiLU + L2 norm (q/k), beta-fold (v) ----------
__global__ __launch_bounds__(128) void prep_conv(
    const float* __restrict__ x,      // [T, QKV]
    const float* __restrict__ w,      // [QKV, 4]
    const float* __restrict__ bgate,  // [T, HV]
    float* __restrict__ qn2,          // [HK][T][DK]
    float* __restrict__ kn2,          // [HK][T][DK]
    float* __restrict__ va2)          // [HV][T][DV]  = beta * v
{
    const int t   = blockIdx.x;
    const int seg = blockIdx.y;
    const int d   = threadIdx.x;
    const int c   = seg * 128 + d;

    const float4 w4 = ((const float4*)w)[c];
    float acc;
    if (t >= 3) {
        const float* xc = x + (size_t)(t - 3) * QKVn + c;
        acc = fmaf(w4.x, xc[0],
              fmaf(w4.y, xc[(size_t)QKVn],
              fmaf(w4.z, xc[(size_t)2 * QKVn],
                   w4.w * xc[(size_t)3 * QKVn])));
    } else {
        float a0 = (t - 3 >= 0) ? x[(size_t)(t - 3) * QKVn + c] : 0.f;
        float a1 = (t - 2 >= 0) ? x[(size_t)(t - 2) * QKVn + c] : 0.f;
        float a2 = (t - 1 >= 0) ? x[(size_t)(t - 1) * QKVn + c] : 0.f;
        float a3 = x[(size_t)t * QKVn + c];
        acc = fmaf(w4.x, a0, fmaf(w4.y, a1, fmaf(w4.z, a2, w4.w * a3)));
    }
    const float y = acc / (1.f + expf(-acc));   // SiLU

    if (seg < 32) {
        float ss = reduce32g(y * y);
        __shared__ float part[4];
        if ((threadIdx.x & 31) == 0) part[threadIdx.x >> 5] = ss;
        __syncthreads();
        const float total = part[0] + part[1] + part[2] + part[3];
        const float r = rsqrtf(total + 1e-6f);
        float o = y * r;
        if (seg < 16) {
            o *= 0.08838834764831845f;               // DK^-0.5
            qn2[((size_t)seg * T_LEN + t) * DKn + d] = o;
        } else {
            kn2[((size_t)(seg - 16) * T_LEN + t) * DKn + d] = o;
        }
    } else {
        const int h = seg - 32;
        const float bv = bgate[(size_t)t * HVn + h];      // uniform across block
        const float beta = 1.f / (1.f + expf(-bv));
        va2[((size_t)h * T_LEN + t) * DVn + d] = y * beta;
    }
}

// ---------- prep 2: gating, packed (lam, lam*beta) head-major ----------
__global__ __launch_bounds__(256) void prep_gate(
    const float* __restrict__ a,        // [T, HV]
    const float* __restrict__ b,        // [T, HV]
    const float* __restrict__ dt_bias,  // [HV]
    const float* __restrict__ alog,     // [HV]
    float2* __restrict__ gb)            // [HV][T] of (lam, lam*beta)
{
    const int i = blockIdx.x * 256 + threadIdx.x;
    if (i < T_LEN * HVn) {
        const int t = i & (T_LEN - 1);
        const int h = i >> 12;
        const float av = a[(size_t)t * HVn + h];
        const float bv = b[(size_t)t * HVn + h];
        const float xv = av + dt_bias[h];
        const float sp = fmaxf(xv, 0.f) + log1pf(expf(-fabsf(xv)));
        const float g  = -expf(alog[h]) * sp;
        const float lam = expf(g);
        const float beta = 1.f / (1.f + expf(-bv));
        gb[(size_t)h * T_LEN + t] = make_float2(lam, lam * beta);
    }
}

// ---------- scan: ping-pong register double-buffer, 8-step groups ----------
struct GroupBuf {
    float4 k[8];
    float4 q[8];
    float  v[8];
    float4 g[4];   // steps 2m,2m+1 -> (lam_e, lamb_e, lam_o, lamb_o)
};

__device__ __forceinline__ void issue_group(GroupBuf& B,
    const float*& kL, const float*& qL, const float*& vL, const float*& gL) {
    #pragma unroll
    for (int j = 0; j < 8; ++j) B.k[j] = *(const float4*)(kL + j * DKn);
    #pragma unroll
    for (int j = 0; j < 8; ++j) B.q[j] = *(const float4*)(qL + j * DKn);
    #pragma unroll
    for (int j = 0; j < 8; ++j) B.v[j] = vL[j * DVn];
    #pragma unroll
    for (int j = 0; j < 4; ++j) B.g[j] = *(const float4*)(gL + j * 4);
    kL += GS * DKn; qL += GS * DKn; vL += GS * DVn; gL += GS * 2;
}

#define SB0() __builtin_amdgcn_sched_barrier(0)

template <int GI>
__device__ __forceinline__ void compute_group(const GroupBuf& B,
    float& S0, float& S1, float& S2, float& S3,
    float& okeep, int sp) {
    #pragma unroll
    for (int j = 0; j < 8; ++j) {
        const float4 k4 = B.k[j];
        const float4 q4 = B.q[j];
        const float  av = B.v[j];                       // beta*v
        const float lam = (j & 1) ? B.g[j >> 1].z : B.g[j >> 1].x;
        const float c   = (j & 1) ? B.g[j >> 1].w : B.g[j >> 1].y;  // lam*beta
        float pr = fmaf(k4.x, S0, k4.y * S1) + fmaf(k4.z, S2, k4.w * S3);
        pr = reduce32s(pr);
        const float dl = fmaf(-c, pr, av);
        S0 = fmaf(lam, S0, k4.x * dl);
        S1 = fmaf(lam, S1, k4.y * dl);
        S2 = fmaf(lam, S2, k4.z * dl);
        S3 = fmaf(lam, S3, k4.w * dl);
        float oo = fmaf(q4.x, S0, q4.y * S1) + fmaf(q4.z, S2, q4.w * S3);
        oo = reduce32s(oo);
        okeep = (sp == (GI * 8 + j)) ? oo : okeep;
    }
}

__global__ __launch_bounds__(256) void scan_kernel(
    const float* __restrict__ qn2,  // [HK][T][DK]
    const float* __restrict__ kn2,  // [HK][T][DK]
    const float* __restrict__ va2,  // [HV][T][DV]
    const float* __restrict__ gb,   // [HV][T][2]
    float* __restrict__ out)        // [T, HV, DV]
{
    // bijective XCD swizzle: 512 blocks -> 64 consecutive logical blocks per XCD
    int blk = blockIdx.x;
    blk = (blk & 7) * 64 + (blk >> 3);

    const int h    = blk >> 4;             // value head
    const int cg   = blk & 15;             // column group (8 dv)
    const int tid  = threadIdx.x;
    const int wid  = tid >> 6;
    const int lane = tid & 63;
    const int col  = (lane >> 4) & 1;      // colA = rows{0,2}, colB = rows{1,3}
    const int sp   = (lane & 15) | ((lane >> 5) << 4);   // 0..31 dim-slice index
    const int dv   = cg * 8 + wid * 2 + col;
    const int kh   = h >> 1;

    const float* kL = kn2 + (size_t)kh * T_LEN * DKn + (size_t)sp * 4;
    const float* qL = qn2 + (size_t)kh * T_LEN * DKn + (size_t)sp * 4;
    const float* vL = va2 + (size_t)h  * T_LEN * DVn + dv;
    const float* gL = gb  + (size_t)h  * T_LEN * 2;
    float*       oB = out + (size_t)sp * (HVn * DVn) + (size_t)h * DVn + dv;

    float S0 = 0.f, S1 = 0.f, S2 = 0.f, S3 = 0.f;

    GroupBuf A, B;
    issue_group(A, kL, qL, vL, gL);   // group 0
    issue_group(B, kL, qL, vL, gL);   // group 1

    for (int tile = 0; tile < NTI - 1; ++tile) {
        float okeep = 0.f;
        compute_group<0>(A, S0, S1, S2, S3, okeep, sp);
        SB0(); issue_group(A, kL, qL, vL, gL); SB0();
        compute_group<1>(B, S0, S1, S2, S3, okeep, sp);
        SB0(); issue_group(B, kL, qL, vL, gL); SB0();
        compute_group<2>(A, S0, S1, S2, S3, okeep, sp);
        SB0(); issue_group(A, kL, qL, vL, gL); SB0();
        compute_group<3>(B, S0, S1, S2, S3, okeep, sp);
        SB0(); issue_group(B, kL, qL, vL, gL); SB0();
        oB[0] = okeep;
        oB += (size_t)TBO * (HVn * DVn);
    }
    {   // tail tile: groups 508..511; only two more groups (510,511) to load
        float okeep = 0.f;
        compute_group<0>(A, S0, S1, S2, S3, okeep, sp);
        SB0(); issue_group(A, kL, qL, vL, gL); SB0();
        compute_group<1>(B, S0, S1, S2, S3, okeep, sp);
        SB0(); issue_group(B, kL, qL, vL, gL); SB0();
        compute_group<2>(A, S0, S1, S2, S3, okeep, sp);
        compute_group<3>(B, S0, S1, S2, S3, okeep, sp);
        oB[0] = okeep;
    }
}

extern "C" void kernel_launch(void* const* d_in, const int* in_sizes, int n_in,
                              void* d_out, int out_size, void* d_ws, size_t ws_size,
                              hipStream_t stream) {
    const float* mixed_qkv = (const float*)d_in[0];
    const float* a         = (const float*)d_in[1];
    const float* b         = (const float*)d_in[2];
    const float* conv_w    = (const float*)d_in[3];
    const float* dt_bias   = (const float*)d_in[4];
    const float* alog      = (const float*)d_in[5];
    float* out = (float*)d_out;
    float* ws  = (float*)d_ws;

    float* qn2 = ws + QN_OFF;
    float* kn2 = ws + KN_OFF;
    float* va2 = ws + VA_OFF;
    float* gbp = ws + GB_OFF;

    dim3 cgrid(T_LEN, 64);
    prep_conv<<<cgrid, 128, 0, stream>>>(mixed_qkv, conv_w, b, qn2, kn2, va2);

    prep_gate<<<(T_LEN * HVn + 255) / 256, 256, 0, stream>>>(a, b, dt_bias, alog,
                                                             (float2*)gbp);

    scan_kernel<<<HVn * 16, 256, 0, stream>>>(qn2, kn2, va2, gbp, out);
}

// Round 6
// 651.576 us; speedup vs baseline: 2.8715x; 1.2912x over previous
//
#include <hip/hip_runtime.h>

#define T_LEN 4096
#define HKn   16
#define HVn   32
#define DKn   128
#define DVn   128
#define QKVn  8192
#define NCH   64
#define CS    64

typedef __attribute__((ext_vector_type(8))) short short8;
typedef __attribute__((ext_vector_type(4))) float f32x4;

// ---------------- ws byte offsets ----------------
#define OFF_QSH  ((size_t)0)                    // [HK][T][DK] u16
#define OFF_QSL  ((size_t)16777216)
#define OFF_KSH  ((size_t)33554432)
#define OFF_KSL  ((size_t)50331648)
#define OFF_KTH  ((size_t)67108864)             // [HK][DK][T] u16
#define OFF_KTL  ((size_t)83886080)
#define OFF_VA   ((size_t)100663296)            // [HV][T][DV] f32 (beta*v -> U in place)
#define OFF_GBL  ((size_t)167772160)            // [HV][T] float2 (beta, logLam)
#define OFF_G    ((size_t)168820736)            // [HV][T] f32 cumsum G
#define OFF_WH   ((size_t)169345024)            // [HV][NCH][CS][DK] u16 (negated W)
#define OFF_WL   ((size_t)202899456)
#define OFF_MH   ((size_t)236453888)            // [HV][NCH][CS][CS] u16
#define OFF_ML   ((size_t)253231104)
// end ~270MB

// ---------------- helpers ----------------
template <int CTRL>
__device__ __forceinline__ float dpp_add(float x) {
    int v = __builtin_amdgcn_update_dpp(0, __float_as_int(x), CTRL, 0xF, 0xF, true);
    return x + __int_as_float(v);
}
__device__ __forceinline__ float reduce32g(float x) {
    x = dpp_add<0x128>(x); x = dpp_add<0x124>(x);
    x = dpp_add<0x122>(x); x = dpp_add<0x121>(x);
    int v = __builtin_amdgcn_ds_swizzle(__float_as_int(x), 0x401F);
    return x + __int_as_float(v);
}
__device__ __forceinline__ unsigned short bf16rne(float f) {
    unsigned x = __float_as_uint(f);
    return (unsigned short)((x + 0x7FFFu + ((x >> 16) & 1u)) >> 16);
}
__device__ __forceinline__ float bf16tof(unsigned short h) {
    return __uint_as_float(((unsigned)h) << 16);
}
__device__ __forceinline__ void bsplit(float f, unsigned short& h, unsigned short& l) {
    h = bf16rne(f);
    l = bf16rne(f - bf16tof(h));
}
__device__ __forceinline__ f32x4 MF(short8 a, short8 b, f32x4 c) {
    return __builtin_amdgcn_mfma_f32_16x16x32_bf16(a, b, c, 0, 0, 0);
}

// ---------------- prep: gating ----------------
__global__ __launch_bounds__(256) void k_gate(
    const float* __restrict__ a, const float* __restrict__ b,
    const float* __restrict__ dt_bias, const float* __restrict__ alog,
    float2* __restrict__ gbl)
{
    const int i = blockIdx.x * 256 + threadIdx.x;
    if (i < T_LEN * HVn) {
        const int h = i >> 12, t = i & (T_LEN - 1);
        const float av = a[(size_t)t * HVn + h];
        const float bv = b[(size_t)t * HVn + h];
        const float xv = av + dt_bias[h];
        const float sp = fmaxf(xv, 0.f) + log1pf(expf(-fabsf(xv)));
        const float g  = -expf(alog[h]) * sp;          // log lambda
        const float beta = 1.f / (1.f + expf(-bv));
        gbl[(size_t)h * T_LEN + t] = make_float2(beta, g);
    }
}

// ---------------- prep: conv + SiLU + L2norm, bf16-split q/k, beta*v ----------------
__global__ __launch_bounds__(128) void k_conv(
    const float* __restrict__ x, const float* __restrict__ w,
    const float* __restrict__ bgate,
    unsigned short* __restrict__ qsh, unsigned short* __restrict__ qsl,
    unsigned short* __restrict__ ksh, unsigned short* __restrict__ ksl,
    float* __restrict__ va2)
{
    const int t = blockIdx.x, seg = blockIdx.y, d = threadIdx.x;
    const int c = seg * 128 + d;
    const float4 w4 = ((const float4*)w)[c];
    float acc;
    if (t >= 3) {
        const float* xc = x + (size_t)(t - 3) * QKVn + c;
        acc = fmaf(w4.x, xc[0], fmaf(w4.y, xc[(size_t)QKVn],
              fmaf(w4.z, xc[(size_t)2 * QKVn], w4.w * xc[(size_t)3 * QKVn])));
    } else {
        float a0 = (t - 3 >= 0) ? x[(size_t)(t - 3) * QKVn + c] : 0.f;
        float a1 = (t - 2 >= 0) ? x[(size_t)(t - 2) * QKVn + c] : 0.f;
        float a2 = (t - 1 >= 0) ? x[(size_t)(t - 1) * QKVn + c] : 0.f;
        float a3 = x[(size_t)t * QKVn + c];
        acc = fmaf(w4.x, a0, fmaf(w4.y, a1, fmaf(w4.z, a2, w4.w * a3)));
    }
    const float y = acc / (1.f + expf(-acc));

    if (seg < 32) {
        float ss = reduce32g(y * y);
        __shared__ float part[4];
        if ((threadIdx.x & 31) == 0) part[threadIdx.x >> 5] = ss;
        __syncthreads();
        const float total = part[0] + part[1] + part[2] + part[3];
        const float r = rsqrtf(total + 1e-6f);
        float o = y * r;
        unsigned short hh, ll;
        if (seg < 16) {
            o *= 0.08838834764831845f;
            bsplit(o, hh, ll);
            const size_t idx = ((size_t)seg * T_LEN + t) * DKn + d;
            qsh[idx] = hh; qsl[idx] = ll;
        } else {
            bsplit(o, hh, ll);
            const size_t idx = ((size_t)(seg - 16) * T_LEN + t) * DKn + d;
            ksh[idx] = hh; ksl[idx] = ll;
        }
    } else {
        const int h = seg - 32;
        const float bv = bgate[(size_t)t * HVn + h];
        const float beta = 1.f / (1.f + expf(-bv));
        va2[((size_t)h * T_LEN + t) * DVn + d] = y * beta;
    }
}

// ---------------- transpose k -> [HK][DK][T] ----------------
__global__ __launch_bounds__(256) void k_tr(
    const unsigned short* __restrict__ ksh, const unsigned short* __restrict__ ksl,
    unsigned short* __restrict__ kth, unsigned short* __restrict__ ktl)
{
    __shared__ unsigned pk[64][65];
    const int b = blockIdx.x;
    const int kh = b >> 7, tt = (b >> 1) & 63, hh = b & 1;
    const int t0 = tt * 64, d0 = hh * 64;
    const int tid = threadIdx.x;
    #pragma unroll
    for (int e = 0; e < 16; ++e) {
        const int lin = e * 256 + tid;
        const int tl = lin >> 6, dl = lin & 63;
        const size_t o = ((size_t)kh * T_LEN + t0 + tl) * DKn + d0 + dl;
        pk[tl][dl] = ((unsigned)ksh[o] << 16) | (unsigned)ksl[o];
    }
    __syncthreads();
    #pragma unroll
    for (int e = 0; e < 16; ++e) {
        const int lin = e * 256 + tid;
        const int dl = lin >> 6, tl = lin & 63;
        const unsigned v = pk[tl][dl];
        const size_t o = ((size_t)kh * DKn + d0 + dl) * T_LEN + t0 + tl;
        kth[o] = (unsigned short)(v >> 16);
        ktl[o] = (unsigned short)(v & 0xFFFF);
    }
}

// ---------------- phase 1: per (head, chunk): G, A, M, solve -> U (in va2), -W ----------------
__global__ __launch_bounds__(256) void k_p1(
    const float2* __restrict__ gbl,
    const unsigned short* __restrict__ qsh, const unsigned short* __restrict__ qsl,
    const unsigned short* __restrict__ ksh, const unsigned short* __restrict__ ksl,
    float* __restrict__ va2, float* __restrict__ Gbuf,
    unsigned short* __restrict__ Wh, unsigned short* __restrict__ Wl,
    unsigned short* __restrict__ Mh, unsigned short* __restrict__ Ml)
{
    __shared__ float sA[64][68];
    __shared__ float sG[64];
    __shared__ float sB[64];
    const int blk = blockIdx.x;
    const int h = blk >> 6, ch = blk & 63;
    const int kh = h >> 1, t0 = ch * 64;
    const int tid = threadIdx.x, lane = tid & 63, wid = tid >> 6;
    const int l15 = lane & 15, lg = lane >> 4;

    if (tid < 64) {
        float2 g2 = gbl[(size_t)h * T_LEN + t0 + tid];
        sB[tid] = g2.x;
        float G = g2.y;
        #pragma unroll
        for (int s = 1; s < 64; s <<= 1) {
            float y = __int_as_float(__builtin_amdgcn_ds_bpermute((tid - s) << 2, __float_as_int(G)));
            G += (tid >= s) ? y : 0.f;
        }
        sG[tid] = G;
        Gbuf[(size_t)h * T_LEN + t0 + tid] = G;
    }
    __syncthreads();

    // MFMA: KK (strict lower) and QK (lower incl diag), split bf16
    const char TIa[10] = {0,1,1,2,2,2,3,3,3,3};
    const char TJa[10] = {0,0,1,0,1,2,0,1,2,3};
    const size_t kbase = ((size_t)kh * T_LEN + t0) * DKn;
    for (int idx = wid; idx < 10; idx += 4) {
        const int mi = TIa[idx], nj = TJa[idx];
        f32x4 aKK = {0.f,0.f,0.f,0.f}, aQK = {0.f,0.f,0.f,0.f};
        #pragma unroll
        for (int kk = 0; kk < 4; ++kk) {
            const size_t offA = kbase + (size_t)(16*mi + l15) * DKn + 32*kk + 8*lg;
            const size_t offB = kbase + (size_t)(16*nj + l15) * DKn + 32*kk + 8*lg;
            short8 kAh = *(const short8*)(ksh + offA);
            short8 kAl = *(const short8*)(ksl + offA);
            short8 kBh = *(const short8*)(ksh + offB);
            short8 kBl = *(const short8*)(ksl + offB);
            short8 qAh = *(const short8*)(qsh + offA);
            short8 qAl = *(const short8*)(qsl + offA);
            aKK = MF(kAh,kBh,aKK); aKK = MF(kAh,kBl,aKK); aKK = MF(kAl,kBh,aKK);
            aQK = MF(qAh,kBh,aQK); aQK = MF(qAh,kBl,aQK); aQK = MF(qAl,kBh,aQK);
        }
        #pragma unroll
        for (int r = 0; r < 4; ++r) {
            const int i = 16*mi + 4*lg + r;
            const int j = 16*nj + l15;
            const float e = __expf(fminf(sG[i] - sG[j], 0.f));
            sA[i][j] = (j < i) ? sB[i] * e * aKK[r] : 0.f;
            const float mv = (j <= i) ? e * aQK[r] : 0.f;
            unsigned short mh, ml; bsplit(mv, mh, ml);
            const size_t moff = (((size_t)h * NCH + ch) * CS + i) * CS + j;
            Mh[moff] = mh; Ml[moff] = ml;
        }
    }
    __syncthreads();

    // forward substitution: (I+A) X = RHS; cols 0..127 = U (RHS beta*v), 128..255 = W (RHS beta*exp(G)*k)
    const int c = tid;
    float X[64];
    if (c < 128) {
        #pragma unroll
        for (int i = 0; i < 64; ++i)
            X[i] = va2[((size_t)h * T_LEN + t0 + i) * DVn + c];
    } else {
        const int dk = c - 128;
        #pragma unroll
        for (int i = 0; i < 64; ++i) {
            const size_t o = ((size_t)kh * T_LEN + t0 + i) * DKn + dk;
            const float kf = bf16tof(ksh[o]) + bf16tof(ksl[o]);
            X[i] = sB[i] * __expf(sG[i]) * kf;
        }
    }
    #pragma unroll
    for (int i = 1; i < 64; ++i) {
        float acc = X[i];
        const int nq = (i + 3) >> 2;
        #pragma unroll
        for (int q = 0; q < nq; ++q) {
            const f32x4 aa = *(const f32x4*)&sA[i][4*q];
            acc = fmaf(-aa[0], X[4*q+0], acc);
            acc = fmaf(-aa[1], X[4*q+1], acc);
            acc = fmaf(-aa[2], X[4*q+2], acc);
            acc = fmaf(-aa[3], X[4*q+3], acc);
        }
        X[i] = acc;
    }
    if (c < 128) {
        #pragma unroll
        for (int i = 0; i < 64; ++i)
            va2[((size_t)h * T_LEN + t0 + i) * DVn + c] = X[i];   // U in place
    } else {
        const int dk = c - 128;
        #pragma unroll
        for (int i = 0; i < 64; ++i) {
            unsigned short wh, wl; bsplit(-X[i], wh, wl);         // store -W
            const size_t o = (((size_t)h * NCH + ch) * CS + i) * DKn + dk;
            Wh[o] = wh; Wl[o] = wl;
        }
    }
}

// ---------------- phase 2: serial over chunks per (head, dv-slice of 16) ----------------
__global__ __launch_bounds__(256) void k_p2(
    const unsigned short* __restrict__ qsh, const unsigned short* __restrict__ qsl,
    const unsigned short* __restrict__ kth, const unsigned short* __restrict__ ktl,
    const unsigned short* __restrict__ Wh, const unsigned short* __restrict__ Wl,
    const unsigned short* __restrict__ Mh, const unsigned short* __restrict__ Ml,
    const float* __restrict__ va2, const float* __restrict__ Gbuf,
    float* __restrict__ out)
{
    __shared__ float sS[128][17];
    __shared__ unsigned sDL[64][17];
    __shared__ unsigned sDS[64][17];
    __shared__ float sG[64];
    __shared__ float sE[64];

    const int blk = blockIdx.x;
    const int h = blk >> 3, nb = blk & 7;
    const int kh = h >> 1, n0 = nb * 16;
    const int tid = threadIdx.x, lane = tid & 63, wid = tid >> 6;
    const int l15 = lane & 15, lg = lane >> 4;

    for (int z = tid; z < 128 * 17; z += 256) ((float*)sS)[z] = 0.f;
    __syncthreads();

    for (int ch = 0; ch < NCH; ++ch) {
        const int t0 = ch * 64;
        if (tid < 64) sG[tid] = Gbuf[(size_t)h * T_LEN + t0 + tid];
        __syncthreads();
        if (tid < 64) sE[tid] = __expf(sG[63] - sG[tid]);

        // split S into bf16 B-frags (per wave, all kk)
        short8 Sh[4], Sl[4];
        #pragma unroll
        for (int kk = 0; kk < 4; ++kk) {
            #pragma unroll
            for (int j = 0; j < 8; ++j) {
                const float sv = sS[32*kk + 8*lg + j][l15];
                unsigned short hh, ll; bsplit(sv, hh, ll);
                Sh[kk][j] = (short)hh; Sl[kk][j] = (short)ll;
            }
        }
        // DL = U + (-W) @ S
        f32x4 dl;
        #pragma unroll
        for (int r = 0; r < 4; ++r)
            dl[r] = va2[((size_t)h * T_LEN + t0 + 16*wid + 4*lg + r) * DVn + n0 + l15];
        const size_t wbase = (((size_t)h * NCH + ch) * CS + 16*wid + l15) * DKn;
        #pragma unroll
        for (int kk = 0; kk < 4; ++kk) {
            short8 ah = *(const short8*)(Wh + wbase + 32*kk + 8*lg);
            short8 al = *(const short8*)(Wl + wbase + 32*kk + 8*lg);
            dl = MF(ah, Sh[kk], dl); dl = MF(ah, Sl[kk], dl); dl = MF(al, Sh[kk], dl);
        }
        __syncthreads();   // sE ready, prev-chunk DL consumers done

        #pragma unroll
        for (int r = 0; r < 4; ++r) {
            const int cc = 16*wid + 4*lg + r;
            const float f = dl[r];
            unsigned short hh, ll;
            bsplit(f, hh, ll);
            sDL[cc][l15] = ((unsigned)hh << 16) | ll;
            const float fs = f * sE[cc];
            bsplit(fs, hh, ll);
            sDS[cc][l15] = ((unsigned)hh << 16) | ll;
        }
        __syncthreads();   // DL tiles ready

        // O = exp(G_i)*(Q@S) + M@DL
        f32x4 aq = {0.f,0.f,0.f,0.f}, am = {0.f,0.f,0.f,0.f};
        const size_t qbase = ((size_t)kh * T_LEN + t0 + 16*wid + l15) * DKn;
        #pragma unroll
        for (int kk = 0; kk < 4; ++kk) {
            short8 ah = *(const short8*)(qsh + qbase + 32*kk + 8*lg);
            short8 al = *(const short8*)(qsl + qbase + 32*kk + 8*lg);
            aq = MF(ah, Sh[kk], aq); aq = MF(ah, Sl[kk], aq); aq = MF(al, Sh[kk], aq);
        }
        const size_t mbase = (((size_t)h * NCH + ch) * CS + 16*wid + l15) * CS;
        #pragma unroll
        for (int k2 = 0; k2 < 2; ++k2) {
            short8 bh, bl;
            #pragma unroll
            for (int j = 0; j < 8; ++j) {
                const unsigned pk = sDL[32*k2 + 8*lg + j][l15];
                bh[j] = (short)(pk >> 16); bl[j] = (short)(pk & 0xFFFF);
            }
            short8 ah = *(const short8*)(Mh + mbase + 32*k2 + 8*lg);
            short8 al = *(const short8*)(Ml + mbase + 32*k2 + 8*lg);
            am = MF(ah, bh, am); am = MF(ah, bl, am); am = MF(al, bh, am);
        }
        #pragma unroll
        for (int r = 0; r < 4; ++r) {
            const int cc = 16*wid + 4*lg + r;
            const float sc = __expf(sG[cc]);
            out[((size_t)(t0 + cc) * HVn + h) * DVn + n0 + l15] = fmaf(sc, aq[r], am[r]);
        }

        // S' = lam*S + K^T @ (scE .* DL)
        short8 bh2[2], bl2[2];
        #pragma unroll
        for (int k2 = 0; k2 < 2; ++k2) {
            #pragma unroll
            for (int j = 0; j < 8; ++j) {
                const unsigned pk = sDS[32*k2 + 8*lg + j][l15];
                bh2[k2][j] = (short)(pk >> 16); bl2[k2][j] = (short)(pk & 0xFFFF);
            }
        }
        const float lam = __expf(sG[63]);
        #pragma unroll
        for (int m2 = 0; m2 < 2; ++m2) {
            const int mi2 = wid + 4*m2;
            f32x4 t4 = {0.f,0.f,0.f,0.f};
            const size_t kbase2 = ((size_t)kh * DKn + 16*mi2 + l15) * T_LEN + t0;
            #pragma unroll
            for (int k2 = 0; k2 < 2; ++k2) {
                short8 ah = *(const short8*)(kth + kbase2 + 32*k2 + 8*lg);
                short8 al = *(const short8*)(ktl + kbase2 + 32*k2 + 8*lg);
                t4 = MF(ah, bh2[k2], t4); t4 = MF(ah, bl2[k2], t4); t4 = MF(al, bh2[k2], t4);
            }
            #pragma unroll
            for (int r = 0; r < 4; ++r) {
                const int dk = 16*mi2 + 4*lg + r;
                sS[dk][l15] = fmaf(lam, sS[dk][l15], t4[r]);
            }
        }
        __syncthreads();   // S updated, DL tiles free
    }
}

extern "C" void kernel_launch(void* const* d_in, const int* in_sizes, int n_in,
                              void* d_out, int out_size, void* d_ws, size_t ws_size,
                              hipStream_t stream) {
    const float* mixed_qkv = (const float*)d_in[0];
    const float* a         = (const float*)d_in[1];
    const float* b         = (const float*)d_in[2];
    const float* conv_w    = (const float*)d_in[3];
    const float* dt_bias   = (const float*)d_in[4];
    const float* alog      = (const float*)d_in[5];
    float* out = (float*)d_out;
    char* ws = (char*)d_ws;

    unsigned short* qsh = (unsigned short*)(ws + OFF_QSH);
    unsigned short* qsl = (unsigned short*)(ws + OFF_QSL);
    unsigned short* ksh = (unsigned short*)(ws + OFF_KSH);
    unsigned short* ksl = (unsigned short*)(ws + OFF_KSL);
    unsigned short* kth = (unsigned short*)(ws + OFF_KTH);
    unsigned short* ktl = (unsigned short*)(ws + OFF_KTL);
    float*  va2 = (float*)(ws + OFF_VA);
    float2* gbl = (float2*)(ws + OFF_GBL);
    float*  Gbf = (float*)(ws + OFF_G);
    unsigned short* Wh = (unsigned short*)(ws + OFF_WH);
    unsigned short* Wl = (unsigned short*)(ws + OFF_WL);
    unsigned short* Mh = (unsigned short*)(ws + OFF_MH);
    unsigned short* Ml = (unsigned short*)(ws + OFF_ML);

    k_gate<<<(T_LEN * HVn + 255) / 256, 256, 0, stream>>>(a, b, dt_bias, alog, gbl);

    dim3 cgrid(T_LEN, 64);
    k_conv<<<cgrid, 128, 0, stream>>>(mixed_qkv, conv_w, b, qsh, qsl, ksh, ksl, va2);

    k_tr<<<2048, 256, 0, stream>>>(ksh, ksl, kth, ktl);

    k_p1<<<HVn * NCH, 256, 0, stream>>>(gbl, qsh, qsl, ksh, ksl, va2, Gbf, Wh, Wl, Mh, Ml);

    k_p2<<<HVn * 8, 256, 0, stream>>>(qsh, qsl, kth, ktl, Wh, Wl, Mh, Ml, va2, Gbf, out);
}

// Round 7
// 555.275 us; speedup vs baseline: 3.3695x; 1.1734x over previous
//
#include <hip/hip_runtime.h>

#define T_LEN 4096
#define HKn   16
#define HVn   32
#define DKn   128
#define DVn   128
#define QKVn  8192
#define NCH   64
#define CS    64

typedef __attribute__((ext_vector_type(8))) short short8;
typedef __attribute__((ext_vector_type(4))) float f32x4;

// ---------------- ws byte offsets ----------------
#define OFF_QSH  ((size_t)0)                    // [HK][T][DK] u16
#define OFF_QSL  ((size_t)16777216)
#define OFF_KSH  ((size_t)33554432)
#define OFF_KSL  ((size_t)50331648)
#define OFF_KTH  ((size_t)67108864)             // [HK][DK][T] u16
#define OFF_KTL  ((size_t)83886080)
#define OFF_VA   ((size_t)100663296)            // [HV][T][DV] f32 (beta*v -> U in place)
#define OFF_GBL  ((size_t)167772160)            // [HV][T] float2 (beta, logLam)
#define OFF_G    ((size_t)168820736)            // [HV][T] f32 cumsum G
#define OFF_WH   ((size_t)169345024)            // [HV][NCH][CS][DK] u16 (negated W)
#define OFF_WL   ((size_t)202899456)
#define OFF_MH   ((size_t)236453888)            // [HV][NCH][CS][CS] u16
#define OFF_ML   ((size_t)253231104)
// end ~270MB

// ---------------- helpers ----------------
template <int CTRL>
__device__ __forceinline__ float dpp_add(float x) {
    int v = __builtin_amdgcn_update_dpp(0, __float_as_int(x), CTRL, 0xF, 0xF, true);
    return x + __int_as_float(v);
}
__device__ __forceinline__ float reduce32g(float x) {
    x = dpp_add<0x128>(x); x = dpp_add<0x124>(x);
    x = dpp_add<0x122>(x); x = dpp_add<0x121>(x);
    int v = __builtin_amdgcn_ds_swizzle(__float_as_int(x), 0x401F);
    return x + __int_as_float(v);
}
__device__ __forceinline__ unsigned short bf16rne(float f) {
    unsigned x = __float_as_uint(f);
    return (unsigned short)((x + 0x7FFFu + ((x >> 16) & 1u)) >> 16);
}
__device__ __forceinline__ float bf16tof(unsigned short h) {
    return __uint_as_float(((unsigned)h) << 16);
}
__device__ __forceinline__ void bsplit(float f, unsigned short& h, unsigned short& l) {
    h = bf16rne(f);
    l = bf16rne(f - bf16tof(h));
}
__device__ __forceinline__ f32x4 MF(short8 a, short8 b, f32x4 c) {
    return __builtin_amdgcn_mfma_f32_16x16x32_bf16(a, b, c, 0, 0, 0);
}
#define SB0() __builtin_amdgcn_sched_barrier(0)

// ---------------- prep: gating ----------------
__global__ __launch_bounds__(256) void k_gate(
    const float* __restrict__ a, const float* __restrict__ b,
    const float* __restrict__ dt_bias, const float* __restrict__ alog,
    float2* __restrict__ gbl)
{
    const int i = blockIdx.x * 256 + threadIdx.x;
    if (i < T_LEN * HVn) {
        const int h = i >> 12, t = i & (T_LEN - 1);
        const float av = a[(size_t)t * HVn + h];
        const float bv = b[(size_t)t * HVn + h];
        const float xv = av + dt_bias[h];
        const float sp = fmaxf(xv, 0.f) + log1pf(expf(-fabsf(xv)));
        const float g  = -expf(alog[h]) * sp;          // log lambda
        const float beta = 1.f / (1.f + expf(-bv));
        gbl[(size_t)h * T_LEN + t] = make_float2(beta, g);
    }
}

// ---------------- prep: conv + SiLU + L2norm, bf16-split q/k, beta*v ----------------
__global__ __launch_bounds__(128) void k_conv(
    const float* __restrict__ x, const float* __restrict__ w,
    const float* __restrict__ bgate,
    unsigned short* __restrict__ qsh, unsigned short* __restrict__ qsl,
    unsigned short* __restrict__ ksh, unsigned short* __restrict__ ksl,
    float* __restrict__ va2)
{
    const int t = blockIdx.x, seg = blockIdx.y, d = threadIdx.x;
    const int c = seg * 128 + d;
    const float4 w4 = ((const float4*)w)[c];
    float acc;
    if (t >= 3) {
        const float* xc = x + (size_t)(t - 3) * QKVn + c;
        acc = fmaf(w4.x, xc[0], fmaf(w4.y, xc[(size_t)QKVn],
              fmaf(w4.z, xc[(size_t)2 * QKVn], w4.w * xc[(size_t)3 * QKVn])));
    } else {
        float a0 = (t - 3 >= 0) ? x[(size_t)(t - 3) * QKVn + c] : 0.f;
        float a1 = (t - 2 >= 0) ? x[(size_t)(t - 2) * QKVn + c] : 0.f;
        float a2 = (t - 1 >= 0) ? x[(size_t)(t - 1) * QKVn + c] : 0.f;
        float a3 = x[(size_t)t * QKVn + c];
        acc = fmaf(w4.x, a0, fmaf(w4.y, a1, fmaf(w4.z, a2, w4.w * a3)));
    }
    const float y = acc / (1.f + expf(-acc));

    if (seg < 32) {
        float ss = reduce32g(y * y);
        __shared__ float part[4];
        if ((threadIdx.x & 31) == 0) part[threadIdx.x >> 5] = ss;
        __syncthreads();
        const float total = part[0] + part[1] + part[2] + part[3];
        const float r = rsqrtf(total + 1e-6f);
        float o = y * r;
        unsigned short hh, ll;
        if (seg < 16) {
            o *= 0.08838834764831845f;
            bsplit(o, hh, ll);
            const size_t idx = ((size_t)seg * T_LEN + t) * DKn + d;
            qsh[idx] = hh; qsl[idx] = ll;
        } else {
            bsplit(o, hh, ll);
            const size_t idx = ((size_t)(seg - 16) * T_LEN + t) * DKn + d;
            ksh[idx] = hh; ksl[idx] = ll;
        }
    } else {
        const int h = seg - 32;
        const float bv = bgate[(size_t)t * HVn + h];
        const float beta = 1.f / (1.f + expf(-bv));
        va2[((size_t)h * T_LEN + t) * DVn + d] = y * beta;
    }
}

// ---------------- transpose k -> [HK][DK][T] ----------------
__global__ __launch_bounds__(256) void k_tr(
    const unsigned short* __restrict__ ksh, const unsigned short* __restrict__ ksl,
    unsigned short* __restrict__ kth, unsigned short* __restrict__ ktl)
{
    __shared__ unsigned pk[64][65];
    const int b = blockIdx.x;
    const int kh = b >> 7, tt = (b >> 1) & 63, hh = b & 1;
    const int t0 = tt * 64, d0 = hh * 64;
    const int tid = threadIdx.x;
    #pragma unroll
    for (int e = 0; e < 16; ++e) {
        const int lin = e * 256 + tid;
        const int tl = lin >> 6, dl = lin & 63;
        const size_t o = ((size_t)kh * T_LEN + t0 + tl) * DKn + d0 + dl;
        pk[tl][dl] = ((unsigned)ksh[o] << 16) | (unsigned)ksl[o];
    }
    __syncthreads();
    #pragma unroll
    for (int e = 0; e < 16; ++e) {
        const int lin = e * 256 + tid;
        const int dl = lin >> 6, tl = lin & 63;
        const unsigned v = pk[tl][dl];
        const size_t o = ((size_t)kh * DKn + d0 + dl) * T_LEN + t0 + tl;
        kth[o] = (unsigned short)(v >> 16);
        ktl[o] = (unsigned short)(v & 0xFFFF);
    }
}

// ---------------- phase 1: per (head, chunk): G, A, M, solve -> U (in va2), -W ----------------
__global__ __launch_bounds__(256) void k_p1(
    const float2* __restrict__ gbl,
    const unsigned short* __restrict__ qsh, const unsigned short* __restrict__ qsl,
    const unsigned short* __restrict__ ksh, const unsigned short* __restrict__ ksl,
    float* __restrict__ va2, float* __restrict__ Gbuf,
    unsigned short* __restrict__ Wh, unsigned short* __restrict__ Wl,
    unsigned short* __restrict__ Mh, unsigned short* __restrict__ Ml)
{
    __shared__ float sA[64][68];
    __shared__ float sG[64];
    __shared__ float sB[64];
    const int blk = blockIdx.x;
    const int h = blk >> 6, ch = blk & 63;
    const int kh = h >> 1, t0 = ch * 64;
    const int tid = threadIdx.x, lane = tid & 63, wid = tid >> 6;
    const int l15 = lane & 15, lg = lane >> 4;

    if (tid < 64) {
        float2 g2 = gbl[(size_t)h * T_LEN + t0 + tid];
        sB[tid] = g2.x;
        float G = g2.y;
        #pragma unroll
        for (int s = 1; s < 64; s <<= 1) {
            float y = __int_as_float(__builtin_amdgcn_ds_bpermute((tid - s) << 2, __float_as_int(G)));
            G += (tid >= s) ? y : 0.f;
        }
        sG[tid] = G;
        Gbuf[(size_t)h * T_LEN + t0 + tid] = G;
    }
    __syncthreads();

    // MFMA: KK (strict lower) and QK (lower incl diag), split bf16
    const char TIa[10] = {0,1,1,2,2,2,3,3,3,3};
    const char TJa[10] = {0,0,1,0,1,2,0,1,2,3};
    const size_t kbase = ((size_t)kh * T_LEN + t0) * DKn;
    for (int idx = wid; idx < 10; idx += 4) {
        const int mi = TIa[idx], nj = TJa[idx];
        f32x4 aKK = {0.f,0.f,0.f,0.f}, aQK = {0.f,0.f,0.f,0.f};
        #pragma unroll
        for (int kk = 0; kk < 4; ++kk) {
            const size_t offA = kbase + (size_t)(16*mi + l15) * DKn + 32*kk + 8*lg;
            const size_t offB = kbase + (size_t)(16*nj + l15) * DKn + 32*kk + 8*lg;
            short8 kAh = *(const short8*)(ksh + offA);
            short8 kAl = *(const short8*)(ksl + offA);
            short8 kBh = *(const short8*)(ksh + offB);
            short8 kBl = *(const short8*)(ksl + offB);
            short8 qAh = *(const short8*)(qsh + offA);
            short8 qAl = *(const short8*)(qsl + offA);
            aKK = MF(kAh,kBh,aKK); aKK = MF(kAh,kBl,aKK); aKK = MF(kAl,kBh,aKK);
            aQK = MF(qAh,kBh,aQK); aQK = MF(qAh,kBl,aQK); aQK = MF(qAl,kBh,aQK);
        }
        #pragma unroll
        for (int r = 0; r < 4; ++r) {
            const int i = 16*mi + 4*lg + r;
            const int j = 16*nj + l15;
            const float e = __expf(fminf(sG[i] - sG[j], 0.f));
            sA[i][j] = (j < i) ? sB[i] * e * aKK[r] : 0.f;
            const float mv = (j <= i) ? e * aQK[r] : 0.f;
            unsigned short mh, ml; bsplit(mv, mh, ml);
            const size_t moff = (((size_t)h * NCH + ch) * CS + i) * CS + j;
            Mh[moff] = mh; Ml[moff] = ml;
        }
    }
    __syncthreads();

    // forward substitution: (I+A) X = RHS; cols 0..127 = U (RHS beta*v), 128..255 = W (RHS beta*exp(G)*k)
    const int c = tid;
    float X[64];
    if (c < 128) {
        #pragma unroll
        for (int i = 0; i < 64; ++i)
            X[i] = va2[((size_t)h * T_LEN + t0 + i) * DVn + c];
    } else {
        const int dk = c - 128;
        #pragma unroll
        for (int i = 0; i < 64; ++i) {
            const size_t o = ((size_t)kh * T_LEN + t0 + i) * DKn + dk;
            const float kf = bf16tof(ksh[o]) + bf16tof(ksl[o]);
            X[i] = sB[i] * __expf(sG[i]) * kf;
        }
    }
    #pragma unroll
    for (int i = 1; i < 64; ++i) {
        float acc = X[i];
        const int nq = (i + 3) >> 2;
        #pragma unroll
        for (int q = 0; q < nq; ++q) {
            const f32x4 aa = *(const f32x4*)&sA[i][4*q];
            acc = fmaf(-aa[0], X[4*q+0], acc);
            acc = fmaf(-aa[1], X[4*q+1], acc);
            acc = fmaf(-aa[2], X[4*q+2], acc);
            acc = fmaf(-aa[3], X[4*q+3], acc);
        }
        X[i] = acc;
    }
    if (c < 128) {
        #pragma unroll
        for (int i = 0; i < 64; ++i)
            va2[((size_t)h * T_LEN + t0 + i) * DVn + c] = X[i];   // U in place
    } else {
        const int dk = c - 128;
        #pragma unroll
        for (int i = 0; i < 64; ++i) {
            unsigned short wh, wl; bsplit(-X[i], wh, wl);         // store -W
            const size_t o = (((size_t)h * NCH + ch) * CS + i) * DKn + dk;
            Wh[o] = wh; Wl[o] = wl;
        }
    }
}

// ---------------- phase 2: serial over chunks, register ping-pong prefetch ----------------
struct ChBuf {
    short8 qh[4], ql[4];
    short8 wh[4], wl[4];
    short8 mh[2], ml[2];
    short8 th[2][2], tl[2][2];
    float  u[4];
    float  gv;
};

__device__ __forceinline__ void issue_ch(ChBuf& B, int ch,
    const unsigned short* __restrict__ qsh, const unsigned short* __restrict__ qsl,
    const unsigned short* __restrict__ kth, const unsigned short* __restrict__ ktl,
    const unsigned short* __restrict__ Wh, const unsigned short* __restrict__ Wl,
    const unsigned short* __restrict__ Mh, const unsigned short* __restrict__ Ml,
    const float* __restrict__ va2, const float* __restrict__ Gbuf,
    int h, int kh, int n0, int wid, int l15, int lg, int tid)
{
    const int t0 = ch * CS;
    const size_t qbase = ((size_t)kh * T_LEN + t0 + 16*wid + l15) * DKn;
    #pragma unroll
    for (int kk = 0; kk < 4; ++kk) {
        B.qh[kk] = *(const short8*)(qsh + qbase + 32*kk + 8*lg);
        B.ql[kk] = *(const short8*)(qsl + qbase + 32*kk + 8*lg);
    }
    const size_t wbase = (((size_t)h * NCH + ch) * CS + 16*wid + l15) * DKn;
    #pragma unroll
    for (int kk = 0; kk < 4; ++kk) {
        B.wh[kk] = *(const short8*)(Wh + wbase + 32*kk + 8*lg);
        B.wl[kk] = *(const short8*)(Wl + wbase + 32*kk + 8*lg);
    }
    const size_t mbase = (((size_t)h * NCH + ch) * CS + 16*wid + l15) * CS;
    #pragma unroll
    for (int k2 = 0; k2 < 2; ++k2) {
        B.mh[k2] = *(const short8*)(Mh + mbase + 32*k2 + 8*lg);
        B.ml[k2] = *(const short8*)(Ml + mbase + 32*k2 + 8*lg);
    }
    #pragma unroll
    for (int m2 = 0; m2 < 2; ++m2) {
        const size_t kb2 = ((size_t)kh * DKn + 16*(wid + 4*m2) + l15) * T_LEN + t0;
        #pragma unroll
        for (int k2 = 0; k2 < 2; ++k2) {
            B.th[m2][k2] = *(const short8*)(kth + kb2 + 32*k2 + 8*lg);
            B.tl[m2][k2] = *(const short8*)(ktl + kb2 + 32*k2 + 8*lg);
        }
    }
    #pragma unroll
    for (int r = 0; r < 4; ++r)
        B.u[r] = va2[((size_t)h * T_LEN + t0 + 16*wid + 4*lg + r) * DVn + n0 + l15];
    B.gv = Gbuf[(size_t)h * T_LEN + t0 + (tid & 63)];
}

__device__ __forceinline__ void compute_ch(const ChBuf& B, int ch,
    float (*sS)[17], unsigned (*sDL)[17], unsigned (*sDS)[17],
    float* sG, float* sE, float* __restrict__ out,
    int h, int n0, int wid, int l15, int lg, int tid)
{
    const int t0 = ch * CS;
    if (tid < 64) sG[tid] = B.gv;
    __syncthreads();
    if (tid < 64) sE[tid] = __expf(sG[63] - sG[tid]);

    // split S into bf16 B-frags
    short8 Sh[4], Sl[4];
    #pragma unroll
    for (int kk = 0; kk < 4; ++kk) {
        #pragma unroll
        for (int j = 0; j < 8; ++j) {
            const float sv = sS[32*kk + 8*lg + j][l15];
            unsigned short hh, ll; bsplit(sv, hh, ll);
            Sh[kk][j] = (short)hh; Sl[kk][j] = (short)ll;
        }
    }
    // DL = U + (-W) @ S
    f32x4 dl;
    #pragma unroll
    for (int r = 0; r < 4; ++r) dl[r] = B.u[r];
    #pragma unroll
    for (int kk = 0; kk < 4; ++kk) {
        dl = MF(B.wh[kk], Sh[kk], dl); dl = MF(B.wh[kk], Sl[kk], dl); dl = MF(B.wl[kk], Sh[kk], dl);
    }
    __syncthreads();

    #pragma unroll
    for (int r = 0; r < 4; ++r) {
        const int cc = 16*wid + 4*lg + r;
        unsigned short hh, ll;
        bsplit(dl[r], hh, ll);
        sDL[cc][l15] = ((unsigned)hh << 16) | ll;
        const float fs = dl[r] * sE[cc];
        bsplit(fs, hh, ll);
        sDS[cc][l15] = ((unsigned)hh << 16) | ll;
    }
    __syncthreads();

    // O = exp(G_i)*(Q@S) + M@DL
    f32x4 aq = {0.f,0.f,0.f,0.f}, am = {0.f,0.f,0.f,0.f};
    #pragma unroll
    for (int kk = 0; kk < 4; ++kk) {
        aq = MF(B.qh[kk], Sh[kk], aq); aq = MF(B.qh[kk], Sl[kk], aq); aq = MF(B.ql[kk], Sh[kk], aq);
    }
    #pragma unroll
    for (int k2 = 0; k2 < 2; ++k2) {
        short8 bh, bl;
        #pragma unroll
        for (int j = 0; j < 8; ++j) {
            const unsigned pk = sDL[32*k2 + 8*lg + j][l15];
            bh[j] = (short)(pk >> 16); bl[j] = (short)(pk & 0xFFFF);
        }
        am = MF(B.mh[k2], bh, am); am = MF(B.mh[k2], bl, am); am = MF(B.ml[k2], bh, am);
    }
    #pragma unroll
    for (int r = 0; r < 4; ++r) {
        const int cc = 16*wid + 4*lg + r;
        const float sc = __expf(sG[cc]);
        out[((size_t)(t0 + cc) * HVn + h) * DVn + n0 + l15] = fmaf(sc, aq[r], am[r]);
    }

    // S' = lam*S + K^T @ (scE .* DL)
    short8 bh2[2], bl2[2];
    #pragma unroll
    for (int k2 = 0; k2 < 2; ++k2) {
        #pragma unroll
        for (int j = 0; j < 8; ++j) {
            const unsigned pk = sDS[32*k2 + 8*lg + j][l15];
            bh2[k2][j] = (short)(pk >> 16); bl2[k2][j] = (short)(pk & 0xFFFF);
        }
    }
    const float lam = __expf(sG[63]);
    #pragma unroll
    for (int m2 = 0; m2 < 2; ++m2) {
        f32x4 t4 = {0.f,0.f,0.f,0.f};
        #pragma unroll
        for (int k2 = 0; k2 < 2; ++k2) {
            t4 = MF(B.th[m2][k2], bh2[k2], t4); t4 = MF(B.th[m2][k2], bl2[k2], t4); t4 = MF(B.tl[m2][k2], bh2[k2], t4);
        }
        #pragma unroll
        for (int r = 0; r < 4; ++r) {
            const int dk = 16*(wid + 4*m2) + 4*lg + r;
            sS[dk][l15] = fmaf(lam, sS[dk][l15], t4[r]);
        }
    }
    __syncthreads();
}

__global__ __launch_bounds__(256, 1) void k_p2(
    const unsigned short* __restrict__ qsh, const unsigned short* __restrict__ qsl,
    const unsigned short* __restrict__ kth, const unsigned short* __restrict__ ktl,
    const unsigned short* __restrict__ Wh, const unsigned short* __restrict__ Wl,
    const unsigned short* __restrict__ Mh, const unsigned short* __restrict__ Ml,
    const float* __restrict__ va2, const float* __restrict__ Gbuf,
    float* __restrict__ out)
{
    __shared__ float sS[128][17];
    __shared__ unsigned sDL[64][17];
    __shared__ unsigned sDS[64][17];
    __shared__ float sG[64];
    __shared__ float sE[64];

    // XCD co-location: physical p -> xcd = p&7 (HW round-robin); all 8 slices of a
    // head share an XCD; 4 heads per XCD.
    const int p = blockIdx.x;
    const int slot = p >> 3;
    const int h  = (p & 7) * 4 + (slot & 3);   // value head
    const int nb = slot >> 2;                  // dv-slice 0..7
    const int kh = h >> 1, n0 = nb * 16;
    const int tid = threadIdx.x, lane = tid & 63, wid = tid >> 6;
    const int l15 = lane & 15, lg = lane >> 4;

    for (int z = tid; z < 128 * 17; z += 256) ((float*)sS)[z] = 0.f;
    __syncthreads();

    ChBuf bufA, bufB;
    issue_ch(bufA, 0, qsh, qsl, kth, ktl, Wh, Wl, Mh, Ml, va2, Gbuf,
             h, kh, n0, wid, l15, lg, tid);

    #pragma unroll 1
    for (int ch2 = 0; ch2 < NCH / 2; ++ch2) {
        const int ch = 2 * ch2;
        SB0();
        issue_ch(bufB, ch + 1, qsh, qsl, kth, ktl, Wh, Wl, Mh, Ml, va2, Gbuf,
                 h, kh, n0, wid, l15, lg, tid);
        SB0();
        compute_ch(bufA, ch, sS, sDL, sDS, sG, sE, out, h, n0, wid, l15, lg, tid);
        SB0();
        if (ch + 2 < NCH)
            issue_ch(bufA, ch + 2, qsh, qsl, kth, ktl, Wh, Wl, Mh, Ml, va2, Gbuf,
                     h, kh, n0, wid, l15, lg, tid);
        SB0();
        compute_ch(bufB, ch + 1, sS, sDL, sDS, sG, sE, out, h, n0, wid, l15, lg, tid);
    }
}

extern "C" void kernel_launch(void* const* d_in, const int* in_sizes, int n_in,
                              void* d_out, int out_size, void* d_ws, size_t ws_size,
                              hipStream_t stream) {
    const float* mixed_qkv = (const float*)d_in[0];
    const float* a         = (const float*)d_in[1];
    const float* b         = (const float*)d_in[2];
    const float* conv_w    = (const float*)d_in[3];
    const float* dt_bias   = (const float*)d_in[4];
    const float* alog      = (const float*)d_in[5];
    float* out = (float*)d_out;
    char* ws = (char*)d_ws;

    unsigned short* qsh = (unsigned short*)(ws + OFF_QSH);
    unsigned short* qsl = (unsigned short*)(ws + OFF_QSL);
    unsigned short* ksh = (unsigned short*)(ws + OFF_KSH);
    unsigned short* ksl = (unsigned short*)(ws + OFF_KSL);
    unsigned short* kth = (unsigned short*)(ws + OFF_KTH);
    unsigned short* ktl = (unsigned short*)(ws + OFF_KTL);
    float*  va2 = (float*)(ws + OFF_VA);
    float2* gbl = (float2*)(ws + OFF_GBL);
    float*  Gbf = (float*)(ws + OFF_G);
    unsigned short* Wh = (unsigned short*)(ws + OFF_WH);
    unsigned short* Wl = (unsigned short*)(ws + OFF_WL);
    unsigned short* Mh = (unsigned short*)(ws + OFF_MH);
    unsigned short* Ml = (unsigned short*)(ws + OFF_ML);

    k_gate<<<(T_LEN * HVn + 255) / 256, 256, 0, stream>>>(a, b, dt_bias, alog, gbl);

    dim3 cgrid(T_LEN, 64);
    k_conv<<<cgrid, 128, 0, stream>>>(mixed_qkv, conv_w, b, qsh, qsl, ksh, ksl, va2);

    k_tr<<<2048, 256, 0, stream>>>(ksh, ksl, kth, ktl);

    k_p1<<<HVn * NCH, 256, 0, stream>>>(gbl, qsh, qsl, ksh, ksl, va2, Gbf, Wh, Wl, Mh, Ml);

    k_p2<<<HVn * 8, 256, 0, stream>>>(qsh, qsl, kth, ktl, Wh, Wl, Mh, Ml, va2, Gbf, out);
}

// Round 8
// 530.961 us; speedup vs baseline: 3.5238x; 1.0458x over previous
//
#include <hip/hip_runtime.h>

#define T_LEN 4096
#define HKn   16
#define HVn   32
#define DKn   128
#define DVn   128
#define QKVn  8192
#define NCH   64
#define CS    64

typedef __attribute__((ext_vector_type(8))) short short8;
typedef __attribute__((ext_vector_type(4))) float f32x4;
typedef __attribute__((ext_vector_type(4))) unsigned u32x4;

// ---------------- ws byte offsets ----------------
#define OFF_QSH  ((size_t)0)                    // [HK][T][DK] u16
#define OFF_QSL  ((size_t)16777216)
#define OFF_KSH  ((size_t)33554432)
#define OFF_KSL  ((size_t)50331648)
#define OFF_KTH  ((size_t)67108864)             // [HK][DK][T] u16
#define OFF_KTL  ((size_t)83886080)
#define OFF_VA   ((size_t)100663296)            // [HV][T][DV] f32 (beta*v -> U in place)
#define OFF_GBL  ((size_t)167772160)            // [HV][T] float2 (beta, logLam)
#define OFF_G    ((size_t)168820736)            // [HV][T] f32 cumsum G
#define OFF_WH   ((size_t)169345024)            // [HV][NCH][CS][DK] u16 (negated W)
#define OFF_WL   ((size_t)202899456)
#define OFF_MH   ((size_t)236453888)            // [HV][NCH][CS][CS] u16
#define OFF_ML   ((size_t)253231104)
// end ~270MB

// ---------------- helpers ----------------
template <int CTRL>
__device__ __forceinline__ float dpp_add(float x) {
    int v = __builtin_amdgcn_update_dpp(0, __float_as_int(x), CTRL, 0xF, 0xF, true);
    return x + __int_as_float(v);
}
__device__ __forceinline__ float reduce32g(float x) {
    x = dpp_add<0x128>(x); x = dpp_add<0x124>(x);
    x = dpp_add<0x122>(x); x = dpp_add<0x121>(x);
    int v = __builtin_amdgcn_ds_swizzle(__float_as_int(x), 0x401F);
    return x + __int_as_float(v);
}
__device__ __forceinline__ unsigned short bf16rne(float f) {
    unsigned x = __float_as_uint(f);
    return (unsigned short)((x + 0x7FFFu + ((x >> 16) & 1u)) >> 16);
}
__device__ __forceinline__ float bf16tof(unsigned short h) {
    return __uint_as_float(((unsigned)h) << 16);
}
__device__ __forceinline__ void bsplit(float f, unsigned short& h, unsigned short& l) {
    h = bf16rne(f);
    l = bf16rne(f - bf16tof(h));
}
__device__ __forceinline__ unsigned packsplit(float f) {
    unsigned short h, l; bsplit(f, h, l);
    return ((unsigned)h << 16) | (unsigned)l;
}
__device__ __forceinline__ f32x4 MF(short8 a, short8 b, f32x4 c) {
    return __builtin_amdgcn_mfma_f32_16x16x32_bf16(a, b, c, 0, 0, 0);
}
// unpack 8 packed u32 (hi<<16|lo) -> hi short8, lo short8
__device__ __forceinline__ void unpack8(u32x4 x0, u32x4 x1, short8& hi, short8& lo) {
    union { u32x4 u; short8 s; } H, L;
    H.u[0] = __builtin_amdgcn_perm(x0.y, x0.x, 0x07060302u);
    L.u[0] = __builtin_amdgcn_perm(x0.y, x0.x, 0x05040100u);
    H.u[1] = __builtin_amdgcn_perm(x0.w, x0.z, 0x07060302u);
    L.u[1] = __builtin_amdgcn_perm(x0.w, x0.z, 0x05040100u);
    H.u[2] = __builtin_amdgcn_perm(x1.y, x1.x, 0x07060302u);
    L.u[2] = __builtin_amdgcn_perm(x1.y, x1.x, 0x05040100u);
    H.u[3] = __builtin_amdgcn_perm(x1.w, x1.z, 0x07060302u);
    L.u[3] = __builtin_amdgcn_perm(x1.w, x1.z, 0x05040100u);
    hi = H.s; lo = L.s;
}
#define SB0() __builtin_amdgcn_sched_barrier(0)

// ---------------- prep: gating ----------------
__global__ __launch_bounds__(256) void k_gate(
    const float* __restrict__ a, const float* __restrict__ b,
    const float* __restrict__ dt_bias, const float* __restrict__ alog,
    float2* __restrict__ gbl)
{
    const int i = blockIdx.x * 256 + threadIdx.x;
    if (i < T_LEN * HVn) {
        const int h = i >> 12, t = i & (T_LEN - 1);
        const float av = a[(size_t)t * HVn + h];
        const float bv = b[(size_t)t * HVn + h];
        const float xv = av + dt_bias[h];
        const float sp = fmaxf(xv, 0.f) + log1pf(expf(-fabsf(xv)));
        const float g  = -expf(alog[h]) * sp;          // log lambda
        const float beta = 1.f / (1.f + expf(-bv));
        gbl[(size_t)h * T_LEN + t] = make_float2(beta, g);
    }
}

// ---------------- prep: conv + SiLU + L2norm, bf16-split q/k, beta*v ----------------
__global__ __launch_bounds__(128) void k_conv(
    const float* __restrict__ x, const float* __restrict__ w,
    const float* __restrict__ bgate,
    unsigned short* __restrict__ qsh, unsigned short* __restrict__ qsl,
    unsigned short* __restrict__ ksh, unsigned short* __restrict__ ksl,
    float* __restrict__ va2)
{
    const int t = blockIdx.x, seg = blockIdx.y, d = threadIdx.x;
    const int c = seg * 128 + d;
    const float4 w4 = ((const float4*)w)[c];
    float acc;
    if (t >= 3) {
        const float* xc = x + (size_t)(t - 3) * QKVn + c;
        acc = fmaf(w4.x, xc[0], fmaf(w4.y, xc[(size_t)QKVn],
              fmaf(w4.z, xc[(size_t)2 * QKVn], w4.w * xc[(size_t)3 * QKVn])));
    } else {
        float a0 = (t - 3 >= 0) ? x[(size_t)(t - 3) * QKVn + c] : 0.f;
        float a1 = (t - 2 >= 0) ? x[(size_t)(t - 2) * QKVn + c] : 0.f;
        float a2 = (t - 1 >= 0) ? x[(size_t)(t - 1) * QKVn + c] : 0.f;
        float a3 = x[(size_t)t * QKVn + c];
        acc = fmaf(w4.x, a0, fmaf(w4.y, a1, fmaf(w4.z, a2, w4.w * a3)));
    }
    const float y = acc / (1.f + expf(-acc));

    if (seg < 32) {
        float ss = reduce32g(y * y);
        __shared__ float part[4];
        if ((threadIdx.x & 31) == 0) part[threadIdx.x >> 5] = ss;
        __syncthreads();
        const float total = part[0] + part[1] + part[2] + part[3];
        const float r = rsqrtf(total + 1e-6f);
        float o = y * r;
        unsigned short hh, ll;
        if (seg < 16) {
            o *= 0.08838834764831845f;
            bsplit(o, hh, ll);
            const size_t idx = ((size_t)seg * T_LEN + t) * DKn + d;
            qsh[idx] = hh; qsl[idx] = ll;
        } else {
            bsplit(o, hh, ll);
            const size_t idx = ((size_t)(seg - 16) * T_LEN + t) * DKn + d;
            ksh[idx] = hh; ksl[idx] = ll;
        }
    } else {
        const int h = seg - 32;
        const float bv = bgate[(size_t)t * HVn + h];
        const float beta = 1.f / (1.f + expf(-bv));
        va2[((size_t)h * T_LEN + t) * DVn + d] = y * beta;
    }
}

// ---------------- transpose k -> [HK][DK][T] ----------------
__global__ __launch_bounds__(256) void k_tr(
    const unsigned short* __restrict__ ksh, const unsigned short* __restrict__ ksl,
    unsigned short* __restrict__ kth, unsigned short* __restrict__ ktl)
{
    __shared__ unsigned pk[64][65];
    const int b = blockIdx.x;
    const int kh = b >> 7, tt = (b >> 1) & 63, hh = b & 1;
    const int t0 = tt * 64, d0 = hh * 64;
    const int tid = threadIdx.x;
    #pragma unroll
    for (int e = 0; e < 16; ++e) {
        const int lin = e * 256 + tid;
        const int tl = lin >> 6, dl = lin & 63;
        const size_t o = ((size_t)kh * T_LEN + t0 + tl) * DKn + d0 + dl;
        pk[tl][dl] = ((unsigned)ksh[o] << 16) | (unsigned)ksl[o];
    }
    __syncthreads();
    #pragma unroll
    for (int e = 0; e < 16; ++e) {
        const int lin = e * 256 + tid;
        const int dl = lin >> 6, tl = lin & 63;
        const unsigned v = pk[tl][dl];
        const size_t o = ((size_t)kh * DKn + d0 + dl) * T_LEN + t0 + tl;
        kth[o] = (unsigned short)(v >> 16);
        ktl[o] = (unsigned short)(v & 0xFFFF);
    }
}

// ---------------- phase 1: per (head, chunk): G, A, M, solve -> U (in va2), -W ----------------
__global__ __launch_bounds__(256) void k_p1(
    const float2* __restrict__ gbl,
    const unsigned short* __restrict__ qsh, const unsigned short* __restrict__ qsl,
    const unsigned short* __restrict__ ksh, const unsigned short* __restrict__ ksl,
    float* __restrict__ va2, float* __restrict__ Gbuf,
    unsigned short* __restrict__ Wh, unsigned short* __restrict__ Wl,
    unsigned short* __restrict__ Mh, unsigned short* __restrict__ Ml)
{
    __shared__ float sA[64][68];
    __shared__ float sG[64];
    __shared__ float sB[64];
    const int blk = blockIdx.x;
    const int h = blk >> 6, ch = blk & 63;
    const int kh = h >> 1, t0 = ch * 64;
    const int tid = threadIdx.x, lane = tid & 63, wid = tid >> 6;
    const int l15 = lane & 15, lg = lane >> 4;

    if (tid < 64) {
        float2 g2 = gbl[(size_t)h * T_LEN + t0 + tid];
        sB[tid] = g2.x;
        float G = g2.y;
        #pragma unroll
        for (int s = 1; s < 64; s <<= 1) {
            float y = __int_as_float(__builtin_amdgcn_ds_bpermute((tid - s) << 2, __float_as_int(G)));
            G += (tid >= s) ? y : 0.f;
        }
        sG[tid] = G;
        Gbuf[(size_t)h * T_LEN + t0 + tid] = G;
    }
    __syncthreads();

    // MFMA: KK (strict lower) and QK (lower incl diag), split bf16
    const char TIa[10] = {0,1,1,2,2,2,3,3,3,3};
    const char TJa[10] = {0,0,1,0,1,2,0,1,2,3};
    const size_t kbase = ((size_t)kh * T_LEN + t0) * DKn;
    for (int idx = wid; idx < 10; idx += 4) {
        const int mi = TIa[idx], nj = TJa[idx];
        f32x4 aKK = {0.f,0.f,0.f,0.f}, aQK = {0.f,0.f,0.f,0.f};
        #pragma unroll
        for (int kk = 0; kk < 4; ++kk) {
            const size_t offA = kbase + (size_t)(16*mi + l15) * DKn + 32*kk + 8*lg;
            const size_t offB = kbase + (size_t)(16*nj + l15) * DKn + 32*kk + 8*lg;
            short8 kAh = *(const short8*)(ksh + offA);
            short8 kAl = *(const short8*)(ksl + offA);
            short8 kBh = *(const short8*)(ksh + offB);
            short8 kBl = *(const short8*)(ksl + offB);
            short8 qAh = *(const short8*)(qsh + offA);
            short8 qAl = *(const short8*)(qsl + offA);
            aKK = MF(kAh,kBh,aKK); aKK = MF(kAh,kBl,aKK); aKK = MF(kAl,kBh,aKK);
            aQK = MF(qAh,kBh,aQK); aQK = MF(qAh,kBl,aQK); aQK = MF(qAl,kBh,aQK);
        }
        #pragma unroll
        for (int r = 0; r < 4; ++r) {
            const int i = 16*mi + 4*lg + r;
            const int j = 16*nj + l15;
            const float e = __expf(fminf(sG[i] - sG[j], 0.f));
            sA[i][j] = (j < i) ? sB[i] * e * aKK[r] : 0.f;
            const float mv = (j <= i) ? e * aQK[r] : 0.f;
            unsigned short mh, ml; bsplit(mv, mh, ml);
            const size_t moff = (((size_t)h * NCH + ch) * CS + i) * CS + j;
            Mh[moff] = mh; Ml[moff] = ml;
        }
    }
    __syncthreads();

    // forward substitution: (I+A) X = RHS; cols 0..127 = U (RHS beta*v), 128..255 = W (RHS beta*exp(G)*k)
    const int c = tid;
    float X[64];
    if (c < 128) {
        #pragma unroll
        for (int i = 0; i < 64; ++i)
            X[i] = va2[((size_t)h * T_LEN + t0 + i) * DVn + c];
    } else {
        const int dk = c - 128;
        #pragma unroll
        for (int i = 0; i < 64; ++i) {
            const size_t o = ((size_t)kh * T_LEN + t0 + i) * DKn + dk;
            const float kf = bf16tof(ksh[o]) + bf16tof(ksl[o]);
            X[i] = sB[i] * __expf(sG[i]) * kf;
        }
    }
    #pragma unroll
    for (int i = 1; i < 64; ++i) {
        float acc = X[i];
        const int nq = (i + 3) >> 2;
        #pragma unroll
        for (int q = 0; q < nq; ++q) {
            const f32x4 aa = *(const f32x4*)&sA[i][4*q];
            acc = fmaf(-aa[0], X[4*q+0], acc);
            acc = fmaf(-aa[1], X[4*q+1], acc);
            acc = fmaf(-aa[2], X[4*q+2], acc);
            acc = fmaf(-aa[3], X[4*q+3], acc);
        }
        X[i] = acc;
    }
    if (c < 128) {
        #pragma unroll
        for (int i = 0; i < 64; ++i)
            va2[((size_t)h * T_LEN + t0 + i) * DVn + c] = X[i];   // U in place
    } else {
        const int dk = c - 128;
        #pragma unroll
        for (int i = 0; i < 64; ++i) {
            unsigned short wh, wl; bsplit(-X[i], wh, wl);         // store -W
            const size_t o = (((size_t)h * NCH + ch) * CS + i) * DKn + dk;
            Wh[o] = wh; Wl[o] = wl;
        }
    }
}

// ---------------- phase 2: S in registers, packed-LDS exchange, 2 barriers/chunk ----------------
struct ChBuf {
    short8 qh[4], ql[4];
    short8 wh[4], wl[4];
    short8 mh[2], ml[2];
    short8 th[2][2], tl[2][2];
    float  u[4];
    float4 g4;
    float  g63;
};

__device__ __forceinline__ void issue_ch(ChBuf& B, int ch,
    const unsigned short* __restrict__ qsh, const unsigned short* __restrict__ qsl,
    const unsigned short* __restrict__ kth, const unsigned short* __restrict__ ktl,
    const unsigned short* __restrict__ Wh, const unsigned short* __restrict__ Wl,
    const unsigned short* __restrict__ Mh, const unsigned short* __restrict__ Ml,
    const float* __restrict__ va2, const float* __restrict__ Gbuf,
    int h, int kh, int n0, int wid, int l15, int lg)
{
    const int t0 = ch * CS;
    const size_t qbase = ((size_t)kh * T_LEN + t0 + 16*wid + l15) * DKn;
    #pragma unroll
    for (int kk = 0; kk < 4; ++kk) {
        B.qh[kk] = *(const short8*)(qsh + qbase + 32*kk + 8*lg);
        B.ql[kk] = *(const short8*)(qsl + qbase + 32*kk + 8*lg);
    }
    const size_t wbase = (((size_t)h * NCH + ch) * CS + 16*wid + l15) * DKn;
    #pragma unroll
    for (int kk = 0; kk < 4; ++kk) {
        B.wh[kk] = *(const short8*)(Wh + wbase + 32*kk + 8*lg);
        B.wl[kk] = *(const short8*)(Wl + wbase + 32*kk + 8*lg);
    }
    const size_t mbase = (((size_t)h * NCH + ch) * CS + 16*wid + l15) * CS;
    #pragma unroll
    for (int k2 = 0; k2 < 2; ++k2) {
        B.mh[k2] = *(const short8*)(Mh + mbase + 32*k2 + 8*lg);
        B.ml[k2] = *(const short8*)(Ml + mbase + 32*k2 + 8*lg);
    }
    #pragma unroll
    for (int m2 = 0; m2 < 2; ++m2) {
        const size_t kb2 = ((size_t)kh * DKn + 16*(wid + 4*m2) + l15) * T_LEN + t0;
        #pragma unroll
        for (int k2 = 0; k2 < 2; ++k2) {
            B.th[m2][k2] = *(const short8*)(kth + kb2 + 32*k2 + 8*lg);
            B.tl[m2][k2] = *(const short8*)(ktl + kb2 + 32*k2 + 8*lg);
        }
    }
    #pragma unroll
    for (int r = 0; r < 4; ++r)
        B.u[r] = va2[((size_t)h * T_LEN + t0 + 16*wid + 4*lg + r) * DVn + n0 + l15];
    const float* gp = Gbuf + (size_t)h * T_LEN + t0;
    B.g4  = *(const float4*)(gp + 16*wid + 4*lg);
    B.g63 = gp[63];
}

__device__ __forceinline__ void compute_ch(const ChBuf& B, int ch,
    unsigned (*sSp)[132], unsigned (*sDLp)[68], unsigned (*sDSp)[68],
    short8* Sbh, short8* Sbl, f32x4* Sc,
    float* __restrict__ out,
    int h, int n0, int wid, int l15, int lg)
{
    const int t0 = ch * CS;
    const float g63 = B.g63;
    const float gr[4] = {B.g4.x, B.g4.y, B.g4.z, B.g4.w};

    // DL = U + (-W) @ S   (S from registers)
    f32x4 dl;
    #pragma unroll
    for (int r = 0; r < 4; ++r) dl[r] = B.u[r];
    #pragma unroll
    for (int kk = 0; kk < 4; ++kk) {
        dl = MF(B.wh[kk], Sbh[kk], dl); dl = MF(B.wh[kk], Sbl[kk], dl); dl = MF(B.wl[kk], Sbh[kk], dl);
    }

    // write packed DL, DS (= DL * exp(G63 - G_t))
    const int cc0 = 16*wid + 4*lg;
    u32x4 pdl, pds;
    #pragma unroll
    for (int r = 0; r < 4; ++r) {
        pdl[r] = packsplit(dl[r]);
        pds[r] = packsplit(dl[r] * __expf(g63 - gr[r]));
    }
    *(u32x4*)&sDLp[l15][cc0] = pdl;
    *(u32x4*)&sDSp[l15][cc0] = pds;
    __syncthreads();                         // barrier 1: DL/DS visible

    // read DL/DS B-frags
    short8 dlh[2], dll[2], dsh[2], dsl[2];
    #pragma unroll
    for (int k2 = 0; k2 < 2; ++k2) {
        u32x4 x0 = *(const u32x4*)&sDLp[l15][32*k2 + 8*lg];
        u32x4 x1 = *(const u32x4*)&sDLp[l15][32*k2 + 8*lg + 4];
        unpack8(x0, x1, dlh[k2], dll[k2]);
        u32x4 y0 = *(const u32x4*)&sDSp[l15][32*k2 + 8*lg];
        u32x4 y1 = *(const u32x4*)&sDSp[l15][32*k2 + 8*lg + 4];
        unpack8(y0, y1, dsh[k2], dsl[k2]);
    }

    // O = exp(G_i)*(Q@S) + M@DL
    f32x4 aq = {0.f,0.f,0.f,0.f}, am = {0.f,0.f,0.f,0.f};
    #pragma unroll
    for (int kk = 0; kk < 4; ++kk) {
        aq = MF(B.qh[kk], Sbh[kk], aq); aq = MF(B.qh[kk], Sbl[kk], aq); aq = MF(B.ql[kk], Sbh[kk], aq);
    }
    #pragma unroll
    for (int k2 = 0; k2 < 2; ++k2) {
        am = MF(B.mh[k2], dlh[k2], am); am = MF(B.mh[k2], dll[k2], am); am = MF(B.ml[k2], dlh[k2], am);
    }
    #pragma unroll
    for (int r = 0; r < 4; ++r) {
        const int cc = cc0 + r;
        out[((size_t)(t0 + cc) * HVn + h) * DVn + n0 + l15] = fmaf(__expf(gr[r]), aq[r], am[r]);
    }

    // S' = lam*S + K^T @ DS  (f32 master in regs), then publish packed split
    const float lam = __expf(g63);
    #pragma unroll
    for (int m2 = 0; m2 < 2; ++m2) {
        f32x4 t4 = {0.f,0.f,0.f,0.f};
        #pragma unroll
        for (int k2 = 0; k2 < 2; ++k2) {
            t4 = MF(B.th[m2][k2], dsh[k2], t4); t4 = MF(B.th[m2][k2], dsl[k2], t4); t4 = MF(B.tl[m2][k2], dsh[k2], t4);
        }
        u32x4 ps;
        #pragma unroll
        for (int r = 0; r < 4; ++r) {
            Sc[m2][r] = fmaf(lam, Sc[m2][r], t4[r]);
            ps[r] = packsplit(Sc[m2][r]);
        }
        *(u32x4*)&sSp[l15][16*wid + 64*m2 + 4*lg] = ps;
    }
    __syncthreads();                         // barrier 2: S visible

    // refresh register B-frag copy of S for next chunk
    #pragma unroll
    for (int kk = 0; kk < 4; ++kk) {
        u32x4 z0 = *(const u32x4*)&sSp[l15][32*kk + 8*lg];
        u32x4 z1 = *(const u32x4*)&sSp[l15][32*kk + 8*lg + 4];
        unpack8(z0, z1, Sbh[kk], Sbl[kk]);
    }
}

__global__ __launch_bounds__(256, 1) void k_p2(
    const unsigned short* __restrict__ qsh, const unsigned short* __restrict__ qsl,
    const unsigned short* __restrict__ kth, const unsigned short* __restrict__ ktl,
    const unsigned short* __restrict__ Wh, const unsigned short* __restrict__ Wl,
    const unsigned short* __restrict__ Mh, const unsigned short* __restrict__ Ml,
    const float* __restrict__ va2, const float* __restrict__ Gbuf,
    float* __restrict__ out)
{
    __shared__ unsigned sSp[16][132];    // packed split S, [col][row dk], stride 132
    __shared__ unsigned sDLp[16][68];    // packed split DL, [col][row t]
    __shared__ unsigned sDSp[16][68];    // packed split DS

    // XCD co-location: all 8 dv-slices of a head on one XCD; 4 heads per XCD.
    const int p = blockIdx.x;
    const int slot = p >> 3;
    const int h  = (p & 7) * 4 + (slot & 3);   // value head
    const int nb = slot >> 2;                  // dv-slice 0..7
    const int kh = h >> 1, n0 = nb * 16;
    const int tid = threadIdx.x, lane = tid & 63, wid = tid >> 6;
    const int l15 = lane & 15, lg = lane >> 4;

    short8 Sbh[4], Sbl[4];
    f32x4 Sc[2];
    const short8 z8 = {0,0,0,0,0,0,0,0};
    #pragma unroll
    for (int kk = 0; kk < 4; ++kk) { Sbh[kk] = z8; Sbl[kk] = z8; }
    Sc[0] = (f32x4){0.f,0.f,0.f,0.f};
    Sc[1] = (f32x4){0.f,0.f,0.f,0.f};

    ChBuf bufA, bufB;
    issue_ch(bufA, 0, qsh, qsl, kth, ktl, Wh, Wl, Mh, Ml, va2, Gbuf,
             h, kh, n0, wid, l15, lg);

    #pragma unroll 1
    for (int ch2 = 0; ch2 < NCH / 2; ++ch2) {
        const int ch = 2 * ch2;
        SB0();
        issue_ch(bufB, ch + 1, qsh, qsl, kth, ktl, Wh, Wl, Mh, Ml, va2, Gbuf,
                 h, kh, n0, wid, l15, lg);
        SB0();
        compute_ch(bufA, ch, sSp, sDLp, sDSp, Sbh, Sbl, Sc, out, h, n0, wid, l15, lg);
        SB0();
        if (ch + 2 < NCH)
            issue_ch(bufA, ch + 2, qsh, qsl, kth, ktl, Wh, Wl, Mh, Ml, va2, Gbuf,
                     h, kh, n0, wid, l15, lg);
        SB0();
        compute_ch(bufB, ch + 1, sSp, sDLp, sDSp, Sbh, Sbl, Sc, out, h, n0, wid, l15, lg);
    }
}

extern "C" void kernel_launch(void* const* d_in, const int* in_sizes, int n_in,
                              void* d_out, int out_size, void* d_ws, size_t ws_size,
                              hipStream_t stream) {
    const float* mixed_qkv = (const float*)d_in[0];
    const float* a         = (const float*)d_in[1];
    const float* b         = (const float*)d_in[2];
    const float* conv_w    = (const float*)d_in[3];
    const float* dt_bias   = (const float*)d_in[4];
    const float* alog      = (const float*)d_in[5];
    float* out = (float*)d_out;
    char* ws = (char*)d_ws;

    unsigned short* qsh = (unsigned short*)(ws + OFF_QSH);
    unsigned short* qsl = (unsigned short*)(ws + OFF_QSL);
    unsigned short* ksh = (unsigned short*)(ws + OFF_KSH);
    unsigned short* ksl = (unsigned short*)(ws + OFF_KSL);
    unsigned short* kth = (unsigned short*)(ws + OFF_KTH);
    unsigned short* ktl = (unsigned short*)(ws + OFF_KTL);
    float*  va2 = (float*)(ws + OFF_VA);
    float2* gbl = (float2*)(ws + OFF_GBL);
    float*  Gbf = (float*)(ws + OFF_G);
    unsigned short* Wh = (unsigned short*)(ws + OFF_WH);
    unsigned short* Wl = (unsigned short*)(ws + OFF_WL);
    unsigned short* Mh = (unsigned short*)(ws + OFF_MH);
    unsigned short* Ml = (unsigned short*)(ws + OFF_ML);

    k_gate<<<(T_LEN * HVn + 255) / 256, 256, 0, stream>>>(a, b, dt_bias, alog, gbl);

    dim3 cgrid(T_LEN, 64);
    k_conv<<<cgrid, 128, 0, stream>>>(mixed_qkv, conv_w, b, qsh, qsl, ksh, ksl, va2);

    k_tr<<<2048, 256, 0, stream>>>(ksh, ksl, kth, ktl);

    k_p1<<<HVn * NCH, 256, 0, stream>>>(gbl, qsh, qsl, ksh, ksl, va2, Gbf, Wh, Wl, Mh, Ml);

    k_p2<<<HVn * 8, 256, 0, stream>>>(qsh, qsl, kth, ktl, Wh, Wl, Mh, Ml, va2, Gbf, out);
}